// Round 1
// baseline (3003.146 us; speedup 1.0000x reference)
//
#include <hip/hip_runtime.h>
#include <math.h>

#define H 256
#define EPS 1e-5f

// ---------- index dtype detection & conversion ----------
// If inputs are int64 (little-endian, values < 2^31), the int32 view has zero
// high words at odd positions. 64 consecutive zero odd-words => int64.
__global__ void detect_i64_k(const int* __restrict__ w, int* __restrict__ flag) {
  if (threadIdx.x == 0 && blockIdx.x == 0) {
    int all0 = 1;
    for (int k = 0; k < 64; k++) if (w[2*k+1] != 0) { all0 = 0; break; }
    *flag = all0;
  }
}

__global__ void convert_idx_k(const void* __restrict__ raw, const int* __restrict__ flag,
                              int* __restrict__ out, int n) {
  int i = blockIdx.x*256 + threadIdx.x;
  if (i >= n) return;
  if (*flag) out[i] = (int)((const long long*)raw)[i];
  else       out[i] = ((const int*)raw)[i];
}

// ---------- graph preprocessing ----------
__global__ void count_edges_k(const int* __restrict__ col, int* __restrict__ cnt, int E_) {
  int e = blockIdx.x*256 + threadIdx.x;
  if (e < E_) atomicAdd(&cnt[col[e]], 1);
}

__global__ void dinv_k(const int* __restrict__ cnt, float* __restrict__ dinv, int N_) {
  int i = blockIdx.x*256 + threadIdx.x;
  if (i < N_) dinv[i] = rsqrtf((float)cnt[i] + 1.0f);
}

// single-block exclusive scan: rowptr[0..N], rowptr[N] = total
__global__ void scan_k(const int* __restrict__ cnt, int* __restrict__ rowptr, int N_) {
  __shared__ int part[1024];
  int t = threadIdx.x;
  int chunk = (N_ + 1023) / 1024;
  int lo = t*chunk, hi = min(lo + chunk, N_);
  int s = 0;
  for (int i = lo; i < hi; i++) s += cnt[i];
  part[t] = s; __syncthreads();
  for (int off = 1; off < 1024; off <<= 1) {
    int v = (t >= off) ? part[t-off] : 0;
    __syncthreads();
    part[t] += v;
    __syncthreads();
  }
  int run = (t == 0) ? 0 : part[t-1];
  for (int i = lo; i < hi; i++) { rowptr[i] = run; run += cnt[i]; }
  if (t == 1023) rowptr[N_] = part[1023];
}

__global__ void fill_csr_k(const int* __restrict__ row, const int* __restrict__ col,
                           const int* __restrict__ rowptr, int* __restrict__ fill,
                           int* __restrict__ src, int E_) {
  int e = blockIdx.x*256 + threadIdx.x;
  if (e < E_) {
    int c = col[e];
    int p = rowptr[c] + atomicAdd(&fill[c], 1);
    src[p] = row[e];
  }
}

__global__ void graph_starts_k(const int* __restrict__ batch, int* __restrict__ gstart,
                               int N_, int G_) {
  int g = blockIdx.x*256 + threadIdx.x;
  if (g > G_) return;
  int lo = 0, hi = N_;
  while (lo < hi) { int m = (lo+hi) >> 1; if (batch[m] < g) lo = m+1; else hi = m; }
  gstart[g] = lo;
}

// ---------- GEMM: C[N][256] = A[N][K] @ W[K][256] ----------
// thread t owns row (blk*256+t); 64-col slab per blockIdx.y; h-tile staged
// transposed in LDS (stride 257 -> conflict-free); W reads are block-uniform
// (scalarized to s_load by the compiler).
__global__ void gemm_k(const float* __restrict__ A, const float* __restrict__ W,
                       float* __restrict__ C, int N_, int K_) {
  __shared__ float ht[64][257];
  int t = threadIdx.x;
  int row0 = blockIdx.x*256;
  int c0 = blockIdx.y*64;
  float acc[64];
#pragma unroll
  for (int c = 0; c < 64; c++) acc[c] = 0.f;

  for (int k0 = 0; k0 < K_; k0 += 64) {
    __syncthreads();
#pragma unroll
    for (int j = 0; j < 64; j++) {
      int idx = j*256 + t;
      int r = idx >> 6, kk = idx & 63;
      int gr = row0 + r;
      ht[kk][r] = (gr < N_) ? A[(size_t)gr*K_ + k0 + kk] : 0.f;
    }
    __syncthreads();
    const float* Wp = W + (size_t)k0*H + c0;
    for (int i = 0; i < 64; i++) {
      float hv = ht[i][t];
      const float* wr = Wp + (size_t)i*H;
#pragma unroll
      for (int c = 0; c < 64; c++) acc[c] = fmaf(hv, wr[c], acc[c]);
    }
  }
  int row = row0 + t;
  if (row < N_) {
    float* Cp = C + (size_t)row*H + c0;
#pragma unroll
    for (int c = 0; c < 64; c += 4) {
      float4 v = make_float4(acc[c], acc[c+1], acc[c+2], acc[c+3]);
      *(float4*)(Cp + c) = v;
    }
  }
}

// ---------- aggregation: agg[c] = dinv[c]*(dinv[c]*xw[c] + sum_r dinv[r]*xw[r]) + b ----------
__global__ void aggregate_k(const float* __restrict__ xw, const int* __restrict__ src,
                            const int* __restrict__ rowptr, const float* __restrict__ dinv,
                            const float* __restrict__ b, float* __restrict__ agg, int N_) {
  int c = blockIdx.x;
  int t = threadIdx.x;
  float di = dinv[c];
  float acc = xw[(size_t)c*H + t] * di;
  int s = rowptr[c], e = rowptr[c+1];
  for (int j = s; j < e; j++) {
    int r = src[j];
    acc = fmaf(dinv[r], xw[(size_t)r*H + t], acc);
  }
  agg[(size_t)c*H + t] = fmaf(acc, di, b[t]);
}

// ---------- batch norm ----------
__global__ void bn_stats_k(const float* __restrict__ agg, float* __restrict__ stats, int N_) {
  int t = threadIdx.x;
  float s = 0.f, s2 = 0.f;
  for (int r = blockIdx.x; r < N_; r += gridDim.x) {
    float v = agg[(size_t)r*H + t];
    s += v; s2 = fmaf(v, v, s2);
  }
  atomicAdd(&stats[t], s);
  atomicAdd(&stats[H+t], s2);
}

__global__ void bn_apply_k(const float* __restrict__ agg, const float* __restrict__ stats,
                           const float* __restrict__ g, const float* __restrict__ beta,
                           float* __restrict__ h, int N_, float invN, int residual) {
  int t = threadIdx.x;
  size_t idx = (size_t)blockIdx.x*H + t;
  float mu  = stats[t]*invN;
  float var = stats[H+t]*invN - mu*mu;
  float x = (agg[idx]-mu)*rsqrtf(var+EPS)*g[t] + beta[t];
  x = fmaxf(x, 0.f);
  h[idx] = residual ? (h[idx] + x) : x;
}

// ---------- pooling + MLP ----------
__global__ void pool_k(const float* __restrict__ h, const int* __restrict__ gstart,
                       float* __restrict__ pooled) {
  int g = blockIdx.x, t = threadIdx.x;
  int s = gstart[g], e = gstart[g+1];
  float sum = 0.f;
  for (int n = s; n < e; n++) sum += h[(size_t)n*H + t];
  float cnt = fmaxf((float)(e - s), 1.f);
  pooled[(size_t)g*H + t] = sum/cnt + sum;
}

__global__ void mlp_k(const float* __restrict__ pooled, const float* __restrict__ mW1,
                      const float* __restrict__ mb1, const float* __restrict__ mW2,
                      const float* __restrict__ mb2, float* __restrict__ out) {
  int g = blockIdx.x, t = threadIdx.x; // 128 threads
  __shared__ float p[H];
  __shared__ float mid[128];
  p[t]       = pooled[(size_t)g*H + t];
  p[t+128]   = pooled[(size_t)g*H + t + 128];
  __syncthreads();
  float a = mb1[t];
  for (int k = 0; k < H; k++) a = fmaf(p[k], mW1[(size_t)k*128 + t], a);
  a = fmaxf(a, 0.f);
  mid[t] = a * mW2[t];
  __syncthreads();
  for (int off = 64; off > 0; off >>= 1) {
    if (t < off) mid[t] += mid[t+off];
    __syncthreads();
  }
  if (t == 0) out[g] = mid[0] + mb2[0];
}

extern "C" void kernel_launch(void* const* d_in, const int* in_sizes, int n_in,
                              void* d_out, int out_size, void* d_ws, size_t ws_size,
                              hipStream_t stream) {
  const float* x        = (const float*)d_in[0];
  const void*  ei_raw   = d_in[1];
  const void*  batch_raw= d_in[2];
  const float* W0 = (const float*)d_in[3];
  const float* b0 = (const float*)d_in[4];
  const float* g0 = (const float*)d_in[5];
  const float* be0= (const float*)d_in[6];
  const float* W1 = (const float*)d_in[7];
  const float* b1 = (const float*)d_in[8];
  const float* g1 = (const float*)d_in[9];
  const float* be1= (const float*)d_in[10];
  const float* W2 = (const float*)d_in[11];
  const float* b2 = (const float*)d_in[12];
  const float* g2 = (const float*)d_in[13];
  const float* be2= (const float*)d_in[14];
  const float* mW1= (const float*)d_in[15];
  const float* mb1= (const float*)d_in[16];
  const float* mW2= (const float*)d_in[17];
  const float* mb2= (const float*)d_in[18];
  float* out = (float*)d_out;

  int N_ = in_sizes[2];
  int E_ = in_sizes[1] / 2;
  int F_ = in_sizes[0] / N_;
  int G_ = out_size;

  char* ws = (char*)d_ws;
  size_t off = 0;
  auto alloc = [&](size_t bytes) -> void* {
    void* p = ws + off;
    off = (off + bytes + 255) & ~(size_t)255;
    return p;
  };
  float* h      = (float*)alloc((size_t)N_*H*4);
  float* xw     = (float*)alloc((size_t)N_*H*4);
  float* agg    = (float*)alloc((size_t)N_*H*4);
  int*   eidx   = (int*)  alloc((size_t)2*E_*4);
  int*   csr    = (int*)  alloc((size_t)E_*4);
  int*   batch  = (int*)  alloc((size_t)N_*4);
  int*   cnt    = (int*)  alloc((size_t)N_*4);
  int*   fill   = (int*)  alloc((size_t)N_*4);
  int*   rowptr = (int*)  alloc((size_t)(N_+1)*4);
  float* dinv   = (float*)alloc((size_t)N_*4);
  float* stats  = (float*)alloc(2*H*4);
  int*   gstart = (int*)  alloc((size_t)(G_+1)*4);
  float* pooled = (float*)alloc((size_t)G_*H*4);
  int*   flag   = (int*)  alloc(4);

  // index preprocessing
  detect_i64_k<<<1, 64, 0, stream>>>((const int*)ei_raw, flag);
  convert_idx_k<<<(2*E_+255)/256, 256, 0, stream>>>(ei_raw, flag, eidx, 2*E_);
  convert_idx_k<<<(N_+255)/256, 256, 0, stream>>>(batch_raw, flag, batch, N_);
  hipMemsetAsync(cnt, 0, (size_t)N_*4, stream);
  hipMemsetAsync(fill, 0, (size_t)N_*4, stream);
  count_edges_k<<<(E_+255)/256, 256, 0, stream>>>(eidx + E_, cnt, E_);
  dinv_k<<<(N_+255)/256, 256, 0, stream>>>(cnt, dinv, N_);
  scan_k<<<1, 1024, 0, stream>>>(cnt, rowptr, N_);
  fill_csr_k<<<(E_+255)/256, 256, 0, stream>>>(eidx, eidx + E_, rowptr, fill, csr, E_);
  graph_starts_k<<<(G_+256)/256, 256, 0, stream>>>(batch, gstart, N_, G_);

  float invN = 1.0f / (float)N_;
  const float* Ws[3]  = {W0, W1, W2};
  const float* bs[3]  = {b0, b1, b2};
  const float* gs[3]  = {g0, g1, g2};
  const float* bes[3] = {be0, be1, be2};

  const float* Ain = x;
  int K_ = F_;
  for (int L = 0; L < 3; L++) {
    dim3 gg((N_+255)/256, 4);
    gemm_k<<<gg, 256, 0, stream>>>(Ain, Ws[L], xw, N_, K_);
    aggregate_k<<<N_, H, 0, stream>>>(xw, csr, rowptr, dinv, bs[L], agg, N_);
    hipMemsetAsync(stats, 0, 2*H*4, stream);
    bn_stats_k<<<256, H, 0, stream>>>(agg, stats, N_);
    bn_apply_k<<<N_, H, 0, stream>>>(agg, stats, gs[L], bes[L], h, N_, invN, L > 0 ? 1 : 0);
    Ain = h; K_ = H;
  }

  pool_k<<<G_, H, 0, stream>>>(h, gstart, pooled);
  mlp_k<<<G_, 128, 0, stream>>>(pooled, mW1, mb1, mW2, mb2, out);
}

// Round 2
// 877.514 us; speedup vs baseline: 3.4223x; 3.4223x over previous
//
#include <hip/hip_runtime.h>
#include <math.h>

#define H 256
#define EPS 1e-5f

typedef __attribute__((ext_vector_type(8))) short bf16x8;
typedef __attribute__((ext_vector_type(4))) float f32x4;

__device__ inline ushort f2b(float f) {
  union { float f; unsigned u; } v; v.f = f;
  unsigned r = v.u + 0x7FFF + ((v.u >> 16) & 1);
  return (ushort)(r >> 16);
}
__device__ inline float b2f(ushort u) {
  union { unsigned u; float f; } v; v.u = ((unsigned)u) << 16;
  return v.f;
}

// ---------- index dtype detection & conversion ----------
__global__ void detect_i64_k(const int* __restrict__ w, int* __restrict__ flag) {
  if (threadIdx.x == 0 && blockIdx.x == 0) {
    int all0 = 1;
    for (int k = 0; k < 64; k++) if (w[2*k+1] != 0) { all0 = 0; break; }
    *flag = all0;
  }
}

__global__ void convert_idx_k(const void* __restrict__ raw, const int* __restrict__ flag,
                              int* __restrict__ out, int n) {
  int i = blockIdx.x*256 + threadIdx.x;
  if (i >= n) return;
  if (*flag) out[i] = (int)((const long long*)raw)[i];
  else       out[i] = ((const int*)raw)[i];
}

// ---------- graph preprocessing ----------
__global__ void count_edges_k(const int* __restrict__ col, int* __restrict__ cnt, int E_) {
  int e = blockIdx.x*256 + threadIdx.x;
  if (e < E_) atomicAdd(&cnt[col[e]], 1);
}

__global__ void dinv_k(const int* __restrict__ cnt, float* __restrict__ dinv, int N_) {
  int i = blockIdx.x*256 + threadIdx.x;
  if (i < N_) dinv[i] = rsqrtf((float)cnt[i] + 1.0f);
}

__global__ void scan_k(const int* __restrict__ cnt, int* __restrict__ rowptr, int N_) {
  __shared__ int part[1024];
  int t = threadIdx.x;
  int chunk = (N_ + 1023) / 1024;
  int lo = t*chunk, hi = min(lo + chunk, N_);
  int s = 0;
  for (int i = lo; i < hi; i++) s += cnt[i];
  part[t] = s; __syncthreads();
  for (int off = 1; off < 1024; off <<= 1) {
    int v = (t >= off) ? part[t-off] : 0;
    __syncthreads();
    part[t] += v;
    __syncthreads();
  }
  int run = (t == 0) ? 0 : part[t-1];
  for (int i = lo; i < hi; i++) { rowptr[i] = run; run += cnt[i]; }
  if (t == 1023) rowptr[N_] = part[1023];
}

__global__ void fill_csr_k(const int* __restrict__ row, const int* __restrict__ col,
                           const int* __restrict__ rowptr, int* __restrict__ fill,
                           int* __restrict__ src, int E_) {
  int e = blockIdx.x*256 + threadIdx.x;
  if (e < E_) {
    int c = col[e];
    int p = rowptr[c] + atomicAdd(&fill[c], 1);
    src[p] = row[e];
  }
}

__global__ void graph_starts_k(const int* __restrict__ batch, int* __restrict__ gstart,
                               int N_, int G_) {
  int g = blockIdx.x*256 + threadIdx.x;
  if (g > G_) return;
  int lo = 0, hi = N_;
  while (lo < hi) { int m = (lo+hi) >> 1; if (batch[m] < g) lo = m+1; else hi = m; }
  gstart[g] = lo;
}

// ---------- fp32 -> bf16 converts ----------
__global__ void xcvt_k(const float* __restrict__ x, ushort* __restrict__ xb, int n4) {
  int i = blockIdx.x*256 + threadIdx.x;
  if (i >= n4) return;
  float4 v = ((const float4*)x)[i];
  ushort4 o; o.x = f2b(v.x); o.y = f2b(v.y); o.z = f2b(v.z); o.w = f2b(v.w);
  ((ushort4*)xb)[i] = o;
}

// Wt[n][k] = bf16(W[k][n]);   idx = n*K + k
__global__ void wt_k(const float* __restrict__ W, ushort* __restrict__ Wt,
                     int kshift, int total) {
  int idx = blockIdx.x*256 + threadIdx.x;
  if (idx >= total) return;
  int n = idx >> kshift;
  int k = idx & ((1 << kshift) - 1);
  Wt[idx] = f2b(W[(size_t)k*H + n]);
}

// ---------- GEMM: y[N][256] = bf16( dinv[row] * (A[N][K] @ W[K][256]) ) ----------
// block = 64 rows x 256 cols, 4 waves; wave w owns 64x64 slab at col w*64.
// All fragments loaded straight from global (A, Wt are L2/L3-resident).
template<int K>
__global__ __launch_bounds__(256) void gemm_mfma_k(
    const ushort* __restrict__ A, const ushort* __restrict__ Wt,
    const float* __restrict__ dinv, ushort* __restrict__ y, int N_) {
  int t = threadIdx.x;
  int lane = t & 63, w = t >> 6;
  int r0 = blockIdx.x * 64;
  int c0 = w * 64;
  int lr = lane & 15, lk = (lane >> 4) * 8;

  f32x4 acc[4][4];
#pragma unroll
  for (int m = 0; m < 4; m++)
#pragma unroll
    for (int n = 0; n < 4; n++) acc[m][n] = (f32x4)0.f;

  const ushort* Ap[4];
#pragma unroll
  for (int m = 0; m < 4; m++) {
    int row = r0 + m*16 + lr; if (row > N_-1) row = N_-1;
    Ap[m] = A + (size_t)row*K + lk;
  }
  const ushort* Wp[4];
#pragma unroll
  for (int n = 0; n < 4; n++) Wp[n] = Wt + (size_t)(c0 + n*16 + lr)*K + lk;

#pragma unroll
  for (int k0 = 0; k0 < K; k0 += 32) {
    bf16x8 a[4], b[4];
#pragma unroll
    for (int m = 0; m < 4; m++) a[m] = *(const bf16x8*)(Ap[m] + k0);
#pragma unroll
    for (int n = 0; n < 4; n++) b[n] = *(const bf16x8*)(Wp[n] + k0);
#pragma unroll
    for (int m = 0; m < 4; m++)
#pragma unroll
      for (int n = 0; n < 4; n++)
        acc[m][n] = __builtin_amdgcn_mfma_f32_16x16x32_bf16(a[m], b[n], acc[m][n], 0, 0, 0);
  }

  int lrow = (lane >> 4) * 4;
  int lcol = lane & 15;
#pragma unroll
  for (int m = 0; m < 4; m++) {
#pragma unroll
    for (int r = 0; r < 4; r++) {
      int row = r0 + m*16 + lrow + r;
      if (row < N_) {
        float dv = dinv[row];
#pragma unroll
        for (int n = 0; n < 4; n++)
          y[(size_t)row*H + c0 + n*16 + lcol] = f2b(acc[m][n][r] * dv);
      }
    }
  }
}

// ---------- aggregation: agg[c] = dinv[c]*(y[c] + sum_r y[r]) + b ----------
// one wave per node; lane owns 4 channels (8B bf16x4 per edge -> 512B/instr)
__global__ void aggregate_k(const ushort* __restrict__ y, const int* __restrict__ src,
                            const int* __restrict__ rowptr, const float* __restrict__ dinv,
                            const float* __restrict__ b, float* __restrict__ agg, int N_) {
  int wid = (blockIdx.x * blockDim.x + threadIdx.x) >> 6;
  int lane = threadIdx.x & 63;
  if (wid >= N_) return;
  int c = wid;
  int ch = lane * 4;
  ushort4 sv = *(const ushort4*)(y + (size_t)c*H + ch);
  float ax = b2f(sv.x), ay = b2f(sv.y), az = b2f(sv.z), aw = b2f(sv.w);
  int s = rowptr[c], e = rowptr[c+1];
  for (int j = s; j < e; j++) {
    int r = src[j];
    ushort4 v = *(const ushort4*)(y + (size_t)r*H + ch);
    ax += b2f(v.x); ay += b2f(v.y); az += b2f(v.z); aw += b2f(v.w);
  }
  float di = dinv[c];
  float4 bv = *(const float4*)(b + ch);
  float4 o;
  o.x = fmaf(ax, di, bv.x);
  o.y = fmaf(ay, di, bv.y);
  o.z = fmaf(az, di, bv.z);
  o.w = fmaf(aw, di, bv.w);
  *(float4*)(agg + (size_t)c*H + ch) = o;
}

// ---------- batch norm ----------
__global__ void bn_stats_k(const float* __restrict__ agg, float* __restrict__ stats, int N_) {
  int t = threadIdx.x;
  float s = 0.f, s2 = 0.f;
  for (int r = blockIdx.x; r < N_; r += gridDim.x) {
    float v = agg[(size_t)r*H + t];
    s += v; s2 = fmaf(v, v, s2);
  }
  atomicAdd(&stats[t], s);
  atomicAdd(&stats[H+t], s2);
}

__global__ void bn_apply_k(const float* __restrict__ agg, const float* __restrict__ stats,
                           const float* __restrict__ g, const float* __restrict__ beta,
                           float* __restrict__ h, ushort* __restrict__ hb,
                           int N_, float invN, int residual) {
  int t = threadIdx.x;
  size_t idx = (size_t)blockIdx.x*H + t;
  float mu  = stats[t]*invN;
  float var = stats[H+t]*invN - mu*mu;
  float x = (agg[idx]-mu)*rsqrtf(var+EPS)*g[t] + beta[t];
  x = fmaxf(x, 0.f);
  float o = residual ? (h[idx] + x) : x;
  h[idx] = o;
  hb[idx] = f2b(o);
}

// ---------- pooling + MLP ----------
__global__ void pool_k(const float* __restrict__ h, const int* __restrict__ gstart,
                       float* __restrict__ pooled) {
  int g = blockIdx.x, t = threadIdx.x;
  int s = gstart[g], e = gstart[g+1];
  float sum = 0.f;
  for (int n = s; n < e; n++) sum += h[(size_t)n*H + t];
  float cnt = fmaxf((float)(e - s), 1.f);
  pooled[(size_t)g*H + t] = sum/cnt + sum;
}

__global__ void mlp_k(const float* __restrict__ pooled, const float* __restrict__ mW1,
                      const float* __restrict__ mb1, const float* __restrict__ mW2,
                      const float* __restrict__ mb2, float* __restrict__ out) {
  int g = blockIdx.x, t = threadIdx.x; // 128 threads
  __shared__ float p[H];
  __shared__ float mid[128];
  p[t]       = pooled[(size_t)g*H + t];
  p[t+128]   = pooled[(size_t)g*H + t + 128];
  __syncthreads();
  float a = mb1[t];
  for (int k = 0; k < H; k++) a = fmaf(p[k], mW1[(size_t)k*128 + t], a);
  a = fmaxf(a, 0.f);
  mid[t] = a * mW2[t];
  __syncthreads();
  for (int off = 64; off > 0; off >>= 1) {
    if (t < off) mid[t] += mid[t+off];
    __syncthreads();
  }
  if (t == 0) out[g] = mid[0] + mb2[0];
}

extern "C" void kernel_launch(void* const* d_in, const int* in_sizes, int n_in,
                              void* d_out, int out_size, void* d_ws, size_t ws_size,
                              hipStream_t stream) {
  const float* x        = (const float*)d_in[0];
  const void*  ei_raw   = d_in[1];
  const void*  batch_raw= d_in[2];
  const float* W0 = (const float*)d_in[3];
  const float* b0 = (const float*)d_in[4];
  const float* g0 = (const float*)d_in[5];
  const float* be0= (const float*)d_in[6];
  const float* W1 = (const float*)d_in[7];
  const float* b1 = (const float*)d_in[8];
  const float* g1 = (const float*)d_in[9];
  const float* be1= (const float*)d_in[10];
  const float* W2 = (const float*)d_in[11];
  const float* b2 = (const float*)d_in[12];
  const float* g2 = (const float*)d_in[13];
  const float* be2= (const float*)d_in[14];
  const float* mW1= (const float*)d_in[15];
  const float* mb1= (const float*)d_in[16];
  const float* mW2= (const float*)d_in[17];
  const float* mb2= (const float*)d_in[18];
  float* out = (float*)d_out;

  int N_ = in_sizes[2];
  int E_ = in_sizes[1] / 2;
  int F_ = in_sizes[0] / N_;
  int G_ = out_size;

  char* ws = (char*)d_ws;
  size_t off = 0;
  auto alloc = [&](size_t bytes) -> void* {
    void* p = ws + off;
    off = (off + bytes + 255) & ~(size_t)255;
    return p;
  };
  float*  h      = (float*) alloc((size_t)N_*H*4);
  float*  agg    = (float*) alloc((size_t)N_*H*4);   // aliased: xb lives here pre-layer0
  ushort* y      = (ushort*)alloc((size_t)N_*H*2);
  ushort* hb     = (ushort*)alloc((size_t)N_*H*2);
  ushort* Wt0    = (ushort*)alloc((size_t)F_*H*2);
  ushort* Wt1    = (ushort*)alloc((size_t)H*H*2);
  ushort* Wt2    = (ushort*)alloc((size_t)H*H*2);
  int*    eidx   = (int*)   alloc((size_t)2*E_*4);
  int*    csr    = (int*)   alloc((size_t)E_*4);
  int*    batch  = (int*)   alloc((size_t)N_*4);
  int*    cnt    = (int*)   alloc((size_t)N_*4);
  int*    fill   = (int*)   alloc((size_t)N_*4);
  int*    rowptr = (int*)   alloc((size_t)(N_+1)*4);
  float*  dinv   = (float*) alloc((size_t)N_*4);
  float*  stats  = (float*) alloc(2*H*4);
  int*    gstart = (int*)   alloc((size_t)(G_+1)*4);
  float*  pooled = (float*) alloc((size_t)G_*H*4);
  int*    flag   = (int*)   alloc(4);
  ushort* xb     = (ushort*)agg;  // alias: dead before aggregate layer0 writes agg

  // index preprocessing
  detect_i64_k<<<1, 64, 0, stream>>>((const int*)ei_raw, flag);
  convert_idx_k<<<(2*E_+255)/256, 256, 0, stream>>>(ei_raw, flag, eidx, 2*E_);
  convert_idx_k<<<(N_+255)/256, 256, 0, stream>>>(batch_raw, flag, batch, N_);
  hipMemsetAsync(cnt, 0, (size_t)N_*4, stream);
  hipMemsetAsync(fill, 0, (size_t)N_*4, stream);
  count_edges_k<<<(E_+255)/256, 256, 0, stream>>>(eidx + E_, cnt, E_);
  dinv_k<<<(N_+255)/256, 256, 0, stream>>>(cnt, dinv, N_);
  scan_k<<<1, 1024, 0, stream>>>(cnt, rowptr, N_);
  fill_csr_k<<<(E_+255)/256, 256, 0, stream>>>(eidx, eidx + E_, rowptr, fill, csr, E_);
  graph_starts_k<<<(G_+256)/256, 256, 0, stream>>>(batch, gstart, N_, G_);

  // weight + input converts
  int ksh0 = 31 - __builtin_clz(F_);
  xcvt_k<<<((N_*F_/4)+255)/256, 256, 0, stream>>>(x, xb, N_*F_/4);
  wt_k<<<((F_*H)+255)/256, 256, 0, stream>>>(W0, Wt0, ksh0, F_*H);
  wt_k<<<((H*H)+255)/256, 256, 0, stream>>>(W1, Wt1, 8, H*H);
  wt_k<<<((H*H)+255)/256, 256, 0, stream>>>(W2, Wt2, 8, H*H);

  float invN = 1.0f / (float)N_;
  const float* bs[3]  = {b0, b1, b2};
  const float* gs[3]  = {g0, g1, g2};
  const float* bes[3] = {be0, be1, be2};
  const ushort* Wts[3] = {Wt0, Wt1, Wt2};

  const ushort* Ain = xb;
  int nb = (N_ + 63) / 64;
  for (int L = 0; L < 3; L++) {
    if (L == 0 && F_ == 128)
      gemm_mfma_k<128><<<nb, 256, 0, stream>>>(Ain, Wts[L], dinv, y, N_);
    else
      gemm_mfma_k<256><<<nb, 256, 0, stream>>>(Ain, Wts[L], dinv, y, N_);
    aggregate_k<<<(N_+3)/4, 256, 0, stream>>>(y, csr, rowptr, dinv, bs[L], agg, N_);
    hipMemsetAsync(stats, 0, 2*H*4, stream);
    bn_stats_k<<<256, H, 0, stream>>>(agg, stats, N_);
    bn_apply_k<<<N_, H, 0, stream>>>(agg, stats, gs[L], bes[L], h, hb, N_, invN, L > 0 ? 1 : 0);
    Ain = hb;
  }

  pool_k<<<G_, H, 0, stream>>>(h, gstart, pooled);
  mlp_k<<<G_, 128, 0, stream>>>(pooled, mW1, mb1, mW2, mb2, out);
}

// Round 3
// 770.271 us; speedup vs baseline: 3.8988x; 1.1392x over previous
//
#include <hip/hip_runtime.h>
#include <math.h>

#define H 256
#define EPS 1e-5f

typedef __attribute__((ext_vector_type(8))) short bf16x8;
typedef __attribute__((ext_vector_type(4))) float f32x4;

__device__ inline ushort f2b(float f) {
  union { float f; unsigned u; } v; v.f = f;
  unsigned r = v.u + 0x7FFF + ((v.u >> 16) & 1);
  return (ushort)(r >> 16);
}
__device__ inline float b2f(ushort u) {
  union { unsigned u; float f; } v; v.u = ((unsigned)u) << 16;
  return v.f;
}

// ---------- index dtype detection & conversion ----------
__global__ void detect_i64_k(const int* __restrict__ w, int* __restrict__ flag) {
  if (threadIdx.x == 0 && blockIdx.x == 0) {
    int all0 = 1;
    for (int k = 0; k < 64; k++) if (w[2*k+1] != 0) { all0 = 0; break; }
    *flag = all0;
  }
}

__global__ void convert_idx_k(const void* __restrict__ raw, const int* __restrict__ flag,
                              int* __restrict__ out, int n) {
  int i = blockIdx.x*256 + threadIdx.x;
  if (i >= n) return;
  if (*flag) out[i] = (int)((const long long*)raw)[i];
  else       out[i] = ((const int*)raw)[i];
}

// ---------- graph preprocessing ----------
__global__ void count_edges_k(const int* __restrict__ col, int* __restrict__ cnt, int E_) {
  int e = blockIdx.x*256 + threadIdx.x;
  if (e < E_) atomicAdd(&cnt[col[e]], 1);
}

__global__ void dinv_k(const int* __restrict__ cnt, float* __restrict__ dinv, int N_) {
  int i = blockIdx.x*256 + threadIdx.x;
  if (i < N_) dinv[i] = rsqrtf((float)cnt[i] + 1.0f);
}

__global__ void scan_k(const int* __restrict__ cnt, int* __restrict__ rowptr, int N_) {
  __shared__ int part[1024];
  int t = threadIdx.x;
  int chunk = (N_ + 1023) / 1024;
  int lo = t*chunk, hi = min(lo + chunk, N_);
  int s = 0;
  for (int i = lo; i < hi; i++) s += cnt[i];
  part[t] = s; __syncthreads();
  for (int off = 1; off < 1024; off <<= 1) {
    int v = (t >= off) ? part[t-off] : 0;
    __syncthreads();
    part[t] += v;
    __syncthreads();
  }
  int run = (t == 0) ? 0 : part[t-1];
  for (int i = lo; i < hi; i++) { rowptr[i] = run; run += cnt[i]; }
  if (t == 1023) rowptr[N_] = part[1023];
}

__global__ void fill_csr_k(const int* __restrict__ row, const int* __restrict__ col,
                           const int* __restrict__ rowptr, int* __restrict__ fill,
                           int* __restrict__ src, int E_) {
  int e = blockIdx.x*256 + threadIdx.x;
  if (e < E_) {
    int c = col[e];
    int p = rowptr[c] + atomicAdd(&fill[c], 1);
    src[p] = row[e];
  }
}

__global__ void graph_starts_k(const int* __restrict__ batch, int* __restrict__ gstart,
                               int N_, int G_) {
  int g = blockIdx.x*256 + threadIdx.x;
  if (g > G_) return;
  int lo = 0, hi = N_;
  while (lo < hi) { int m = (lo+hi) >> 1; if (batch[m] < g) lo = m+1; else hi = m; }
  gstart[g] = lo;
}

// ---------- fp32 -> bf16 converts ----------
__global__ void xcvt_k(const float* __restrict__ x, ushort* __restrict__ xb, int n4) {
  int i = blockIdx.x*256 + threadIdx.x;
  if (i >= n4) return;
  float4 v = ((const float4*)x)[i];
  ushort4 o; o.x = f2b(v.x); o.y = f2b(v.y); o.z = f2b(v.z); o.w = f2b(v.w);
  ((ushort4*)xb)[i] = o;
}

// Wt[n][k] = bf16(W[k][n]);   idx = n*K + k
__global__ void wt_k(const float* __restrict__ W, ushort* __restrict__ Wt,
                     int kshift, int total) {
  int idx = blockIdx.x*256 + threadIdx.x;
  if (idx >= total) return;
  int n = idx >> kshift;
  int k = idx & ((1 << kshift) - 1);
  Wt[idx] = f2b(W[(size_t)k*H + n]);
}

// ---------- GEMM: y[N][256] = bf16( dinv[row] * (A[N][K] @ W[K][256]) ) ----------
template<int K>
__global__ __launch_bounds__(256) void gemm_mfma_k(
    const ushort* __restrict__ A, const ushort* __restrict__ Wt,
    const float* __restrict__ dinv, ushort* __restrict__ y, int N_) {
  int t = threadIdx.x;
  int lane = t & 63, w = t >> 6;
  int r0 = blockIdx.x * 64;
  int c0 = w * 64;
  int lr = lane & 15, lk = (lane >> 4) * 8;

  f32x4 acc[4][4];
#pragma unroll
  for (int m = 0; m < 4; m++)
#pragma unroll
    for (int n = 0; n < 4; n++) acc[m][n] = (f32x4)0.f;

  const ushort* Ap[4];
#pragma unroll
  for (int m = 0; m < 4; m++) {
    int row = r0 + m*16 + lr; if (row > N_-1) row = N_-1;
    Ap[m] = A + (size_t)row*K + lk;
  }
  const ushort* Wp[4];
#pragma unroll
  for (int n = 0; n < 4; n++) Wp[n] = Wt + (size_t)(c0 + n*16 + lr)*K + lk;

#pragma unroll
  for (int k0 = 0; k0 < K; k0 += 32) {
    bf16x8 a[4], b[4];
#pragma unroll
    for (int m = 0; m < 4; m++) a[m] = *(const bf16x8*)(Ap[m] + k0);
#pragma unroll
    for (int n = 0; n < 4; n++) b[n] = *(const bf16x8*)(Wp[n] + k0);
#pragma unroll
    for (int m = 0; m < 4; m++)
#pragma unroll
      for (int n = 0; n < 4; n++)
        acc[m][n] = __builtin_amdgcn_mfma_f32_16x16x32_bf16(a[m], b[n], acc[m][n], 0, 0, 0);
  }

  int lrow = (lane >> 4) * 4;
  int lcol = lane & 15;
#pragma unroll
  for (int m = 0; m < 4; m++) {
#pragma unroll
    for (int r = 0; r < 4; r++) {
      int row = r0 + m*16 + lrow + r;
      if (row < N_) {
        float dv = dinv[row];
#pragma unroll
        for (int n = 0; n < 4; n++)
          y[(size_t)row*H + c0 + n*16 + lcol] = f2b(acc[m][n][r] * dv);
      }
    }
  }
}

// ---------- aggregation + fused BN stats ----------
// grid-stride, one wave per node; lane owns 4 channels. Gather unrolled by 4
// (4 independent accumulators -> 4 loads in flight). Per-thread running
// sum/sumsq reduced via LDS across waves, then 2 global atomics per thread.
__global__ __launch_bounds__(256) void aggregate_k(
    const ushort* __restrict__ y, const int* __restrict__ src,
    const int* __restrict__ rowptr, const float* __restrict__ dinv,
    const float* __restrict__ b, float* __restrict__ agg,
    float* __restrict__ stats, int N_) {
  __shared__ float ls[2*H];
  int t = threadIdx.x;
  ls[t] = 0.f; ls[t + H] = 0.f;
  __syncthreads();

  int lane = t & 63, wv = t >> 6;
  int ch = lane * 4;
  float4 bv = *(const float4*)(b + ch);

  float s0=0.f, s1=0.f, s2=0.f, s3=0.f;
  float q0=0.f, q1=0.f, q2=0.f, q3=0.f;

  for (int c = blockIdx.x*4 + wv; c < N_; c += gridDim.x*4) {
    float di = dinv[c];
    ushort4 sv = *(const ushort4*)(y + (size_t)c*H + ch);
    float a0x = b2f(sv.x), a0y = b2f(sv.y), a0z = b2f(sv.z), a0w = b2f(sv.w);
    float a1x=0.f,a1y=0.f,a1z=0.f,a1w=0.f;
    float a2x=0.f,a2y=0.f,a2z=0.f,a2w=0.f;
    float a3x=0.f,a3y=0.f,a3z=0.f,a3w=0.f;
    int s = rowptr[c], e = rowptr[c+1];
    int j = s;
    for (; j + 4 <= e; j += 4) {
      int r0 = src[j], r1 = src[j+1], r2 = src[j+2], r3 = src[j+3];
      ushort4 v0 = *(const ushort4*)(y + (size_t)r0*H + ch);
      ushort4 v1 = *(const ushort4*)(y + (size_t)r1*H + ch);
      ushort4 v2 = *(const ushort4*)(y + (size_t)r2*H + ch);
      ushort4 v3 = *(const ushort4*)(y + (size_t)r3*H + ch);
      a0x += b2f(v0.x); a0y += b2f(v0.y); a0z += b2f(v0.z); a0w += b2f(v0.w);
      a1x += b2f(v1.x); a1y += b2f(v1.y); a1z += b2f(v1.z); a1w += b2f(v1.w);
      a2x += b2f(v2.x); a2y += b2f(v2.y); a2z += b2f(v2.z); a2w += b2f(v2.w);
      a3x += b2f(v3.x); a3y += b2f(v3.y); a3z += b2f(v3.z); a3w += b2f(v3.w);
    }
    for (; j < e; j++) {
      int r = src[j];
      ushort4 v = *(const ushort4*)(y + (size_t)r*H + ch);
      a0x += b2f(v.x); a0y += b2f(v.y); a0z += b2f(v.z); a0w += b2f(v.w);
    }
    float ax = (a0x + a1x) + (a2x + a3x);
    float ay = (a0y + a1y) + (a2y + a3y);
    float az = (a0z + a1z) + (a2z + a3z);
    float aw = (a0w + a1w) + (a2w + a3w);
    float4 o;
    o.x = fmaf(ax, di, bv.x);
    o.y = fmaf(ay, di, bv.y);
    o.z = fmaf(az, di, bv.z);
    o.w = fmaf(aw, di, bv.w);
    *(float4*)(agg + (size_t)c*H + ch) = o;
    s0 += o.x; q0 = fmaf(o.x, o.x, q0);
    s1 += o.y; q1 = fmaf(o.y, o.y, q1);
    s2 += o.z; q2 = fmaf(o.z, o.z, q2);
    s3 += o.w; q3 = fmaf(o.w, o.w, q3);
  }

  atomicAdd(&ls[ch+0], s0); atomicAdd(&ls[H+ch+0], q0);
  atomicAdd(&ls[ch+1], s1); atomicAdd(&ls[H+ch+1], q1);
  atomicAdd(&ls[ch+2], s2); atomicAdd(&ls[H+ch+2], q2);
  atomicAdd(&ls[ch+3], s3); atomicAdd(&ls[H+ch+3], q3);
  __syncthreads();
  atomicAdd(&stats[t], ls[t]);
  atomicAdd(&stats[H+t], ls[H+t]);
}

// ---------- batch norm apply ----------
__global__ void bn_apply_k(const float* __restrict__ agg, const float* __restrict__ stats,
                           const float* __restrict__ g, const float* __restrict__ beta,
                           float* __restrict__ h, ushort* __restrict__ hb,
                           int N_, float invN, int residual) {
  int t = threadIdx.x;
  size_t idx = (size_t)blockIdx.x*H + t;
  float mu  = stats[t]*invN;
  float var = stats[H+t]*invN - mu*mu;
  float x = (agg[idx]-mu)*rsqrtf(var+EPS)*g[t] + beta[t];
  x = fmaxf(x, 0.f);
  float o = residual ? (h[idx] + x) : x;
  h[idx] = o;
  hb[idx] = f2b(o);
}

// ---------- pooling + MLP ----------
__global__ void pool_k(const float* __restrict__ h, const int* __restrict__ gstart,
                       float* __restrict__ pooled) {
  int g = blockIdx.x, t = threadIdx.x;
  int s = gstart[g], e = gstart[g+1];
  float sum = 0.f;
  for (int n = s; n < e; n++) sum += h[(size_t)n*H + t];
  float cnt = fmaxf((float)(e - s), 1.f);
  pooled[(size_t)g*H + t] = sum/cnt + sum;
}

__global__ void mlp_k(const float* __restrict__ pooled, const float* __restrict__ mW1,
                      const float* __restrict__ mb1, const float* __restrict__ mW2,
                      const float* __restrict__ mb2, float* __restrict__ out) {
  int g = blockIdx.x, t = threadIdx.x; // 128 threads
  __shared__ float p[H];
  __shared__ float mid[128];
  p[t]       = pooled[(size_t)g*H + t];
  p[t+128]   = pooled[(size_t)g*H + t + 128];
  __syncthreads();
  float a = mb1[t];
  for (int k = 0; k < H; k++) a = fmaf(p[k], mW1[(size_t)k*128 + t], a);
  a = fmaxf(a, 0.f);
  mid[t] = a * mW2[t];
  __syncthreads();
  for (int off = 64; off > 0; off >>= 1) {
    if (t < off) mid[t] += mid[t+off];
    __syncthreads();
  }
  if (t == 0) out[g] = mid[0] + mb2[0];
}

extern "C" void kernel_launch(void* const* d_in, const int* in_sizes, int n_in,
                              void* d_out, int out_size, void* d_ws, size_t ws_size,
                              hipStream_t stream) {
  const float* x        = (const float*)d_in[0];
  const void*  ei_raw   = d_in[1];
  const void*  batch_raw= d_in[2];
  const float* W0 = (const float*)d_in[3];
  const float* b0 = (const float*)d_in[4];
  const float* g0 = (const float*)d_in[5];
  const float* be0= (const float*)d_in[6];
  const float* W1 = (const float*)d_in[7];
  const float* b1 = (const float*)d_in[8];
  const float* g1 = (const float*)d_in[9];
  const float* be1= (const float*)d_in[10];
  const float* W2 = (const float*)d_in[11];
  const float* b2 = (const float*)d_in[12];
  const float* g2 = (const float*)d_in[13];
  const float* be2= (const float*)d_in[14];
  const float* mW1= (const float*)d_in[15];
  const float* mb1= (const float*)d_in[16];
  const float* mW2= (const float*)d_in[17];
  const float* mb2= (const float*)d_in[18];
  float* out = (float*)d_out;

  int N_ = in_sizes[2];
  int E_ = in_sizes[1] / 2;
  int F_ = in_sizes[0] / N_;
  int G_ = out_size;

  char* ws = (char*)d_ws;
  size_t off = 0;
  auto alloc = [&](size_t bytes) -> void* {
    void* p = ws + off;
    off = (off + bytes + 255) & ~(size_t)255;
    return p;
  };
  float*  h      = (float*) alloc((size_t)N_*H*4);
  float*  agg    = (float*) alloc((size_t)N_*H*4);   // aliased: xb lives here pre-layer0
  ushort* y      = (ushort*)alloc((size_t)N_*H*2);
  ushort* hb     = (ushort*)alloc((size_t)N_*H*2);
  ushort* Wt0    = (ushort*)alloc((size_t)F_*H*2);
  ushort* Wt1    = (ushort*)alloc((size_t)H*H*2);
  ushort* Wt2    = (ushort*)alloc((size_t)H*H*2);
  int*    eidx   = (int*)   alloc((size_t)2*E_*4);
  int*    csr    = (int*)   alloc((size_t)E_*4);
  int*    batch  = (int*)   alloc((size_t)N_*4);
  int*    cnt    = (int*)   alloc((size_t)N_*4);
  int*    fill   = (int*)   alloc((size_t)N_*4);
  int*    rowptr = (int*)   alloc((size_t)(N_+1)*4);
  float*  dinv   = (float*) alloc((size_t)N_*4);
  float*  stats  = (float*) alloc(2*H*4);
  int*    gstart = (int*)   alloc((size_t)(G_+1)*4);
  float*  pooled = (float*) alloc((size_t)G_*H*4);
  int*    flag   = (int*)   alloc(4);
  ushort* xb     = (ushort*)agg;  // alias: dead before aggregate layer0 writes agg

  // index preprocessing
  detect_i64_k<<<1, 64, 0, stream>>>((const int*)ei_raw, flag);
  convert_idx_k<<<(2*E_+255)/256, 256, 0, stream>>>(ei_raw, flag, eidx, 2*E_);
  convert_idx_k<<<(N_+255)/256, 256, 0, stream>>>(batch_raw, flag, batch, N_);
  hipMemsetAsync(cnt, 0, (size_t)N_*4, stream);
  hipMemsetAsync(fill, 0, (size_t)N_*4, stream);
  count_edges_k<<<(E_+255)/256, 256, 0, stream>>>(eidx + E_, cnt, E_);
  dinv_k<<<(N_+255)/256, 256, 0, stream>>>(cnt, dinv, N_);
  scan_k<<<1, 1024, 0, stream>>>(cnt, rowptr, N_);
  fill_csr_k<<<(E_+255)/256, 256, 0, stream>>>(eidx, eidx + E_, rowptr, fill, csr, E_);
  graph_starts_k<<<(G_+256)/256, 256, 0, stream>>>(batch, gstart, N_, G_);

  // weight + input converts
  int ksh0 = 31 - __builtin_clz(F_);
  xcvt_k<<<((N_*F_/4)+255)/256, 256, 0, stream>>>(x, xb, N_*F_/4);
  wt_k<<<((F_*H)+255)/256, 256, 0, stream>>>(W0, Wt0, ksh0, F_*H);
  wt_k<<<((H*H)+255)/256, 256, 0, stream>>>(W1, Wt1, 8, H*H);
  wt_k<<<((H*H)+255)/256, 256, 0, stream>>>(W2, Wt2, 8, H*H);

  float invN = 1.0f / (float)N_;
  const float* bs[3]  = {b0, b1, b2};
  const float* gs[3]  = {g0, g1, g2};
  const float* bes[3] = {be0, be1, be2};
  const ushort* Wts[3] = {Wt0, Wt1, Wt2};

  const ushort* Ain = xb;
  int nb = (N_ + 63) / 64;
  for (int L = 0; L < 3; L++) {
    if (L == 0 && F_ == 128)
      gemm_mfma_k<128><<<nb, 256, 0, stream>>>(Ain, Wts[L], dinv, y, N_);
    else
      gemm_mfma_k<256><<<nb, 256, 0, stream>>>(Ain, Wts[L], dinv, y, N_);
    hipMemsetAsync(stats, 0, 2*H*4, stream);
    aggregate_k<<<2048, 256, 0, stream>>>(y, csr, rowptr, dinv, bs[L], agg, stats, N_);
    bn_apply_k<<<N_, H, 0, stream>>>(agg, stats, gs[L], bes[L], h, hb, N_, invN, L > 0 ? 1 : 0);
    Ain = hb;
  }

  pool_k<<<G_, H, 0, stream>>>(h, gstart, pooled);
  mlp_k<<<G_, 128, 0, stream>>>(pooled, mW1, mb1, mW2, mb2, out);
}

// Round 4
// 630.558 us; speedup vs baseline: 4.7627x; 1.2216x over previous
//
#include <hip/hip_runtime.h>
#include <math.h>

#define H 256
#define EPS 1e-5f

typedef __attribute__((ext_vector_type(8))) short bf16x8;
typedef __attribute__((ext_vector_type(4))) float f32x4;

__device__ inline ushort f2b(float f) {
  union { float f; unsigned u; } v; v.f = f;
  unsigned r = v.u + 0x7FFF + ((v.u >> 16) & 1);
  return (ushort)(r >> 16);
}
__device__ inline float b2f(ushort u) {
  union { unsigned u; float f; } v; v.u = ((unsigned)u) << 16;
  return v.f;
}

// ---------- index dtype detection & conversion ----------
__global__ void detect_i64_k(const int* __restrict__ w, int* __restrict__ flag) {
  if (threadIdx.x == 0 && blockIdx.x == 0) {
    int all0 = 1;
    for (int k = 0; k < 64; k++) if (w[2*k+1] != 0) { all0 = 0; break; }
    *flag = all0;
  }
}

__global__ void convert_idx_k(const void* __restrict__ raw, const int* __restrict__ flag,
                              int* __restrict__ out, int n) {
  int i = blockIdx.x*256 + threadIdx.x;
  if (i >= n) return;
  if (*flag) out[i] = (int)((const long long*)raw)[i];
  else       out[i] = ((const int*)raw)[i];
}

// ---------- graph preprocessing ----------
__global__ void count_edges_k(const int* __restrict__ col, int* __restrict__ cnt, int E_) {
  int e = blockIdx.x*256 + threadIdx.x;
  if (e < E_) atomicAdd(&cnt[col[e]], 1);
}

__global__ void dinv_k(const int* __restrict__ cnt, float* __restrict__ dinv, int N_) {
  int i = blockIdx.x*256 + threadIdx.x;
  if (i < N_) dinv[i] = rsqrtf((float)cnt[i] + 1.0f);
}

__global__ void scan_k(const int* __restrict__ cnt, int* __restrict__ rowptr, int N_) {
  __shared__ int part[1024];
  int t = threadIdx.x;
  int chunk = (N_ + 1023) / 1024;
  int lo = t*chunk, hi = min(lo + chunk, N_);
  int s = 0;
  for (int i = lo; i < hi; i++) s += cnt[i];
  part[t] = s; __syncthreads();
  for (int off = 1; off < 1024; off <<= 1) {
    int v = (t >= off) ? part[t-off] : 0;
    __syncthreads();
    part[t] += v;
    __syncthreads();
  }
  int run = (t == 0) ? 0 : part[t-1];
  for (int i = lo; i < hi; i++) { rowptr[i] = run; run += cnt[i]; }
  if (t == 1023) rowptr[N_] = part[1023];
}

__global__ void fill_csr_k(const int* __restrict__ row, const int* __restrict__ col,
                           const int* __restrict__ rowptr, int* __restrict__ fill,
                           int* __restrict__ src, int E_) {
  int e = blockIdx.x*256 + threadIdx.x;
  if (e < E_) {
    int c = col[e];
    int p = rowptr[c] + atomicAdd(&fill[c], 1);
    src[p] = row[e];
  }
}

__global__ void graph_starts_k(const int* __restrict__ batch, int* __restrict__ gstart,
                               int N_, int G_) {
  int g = blockIdx.x*256 + threadIdx.x;
  if (g > G_) return;
  int lo = 0, hi = N_;
  while (lo < hi) { int m = (lo+hi) >> 1; if (batch[m] < g) lo = m+1; else hi = m; }
  gstart[g] = lo;
}

// ---------- xs[r][f] = bf16(dinv[r] * x[r][f]) ----------
__global__ void xs_k(const float* __restrict__ x, const float* __restrict__ dinv,
                     ushort* __restrict__ xs, int n4, int F_) {
  int i = blockIdx.x*256 + threadIdx.x;
  if (i >= n4) return;
  int row = (i << 2) / F_;
  float dv = dinv[row];
  float4 v = ((const float4*)x)[i];
  ushort4 o;
  o.x = f2b(v.x*dv); o.y = f2b(v.y*dv); o.z = f2b(v.z*dv); o.w = f2b(v.w*dv);
  ((ushort4*)xs)[i] = o;
}

// Wt[n][k] = bf16(W[k][n]);   idx = n*K + k
__global__ void wt_k(const float* __restrict__ W, ushort* __restrict__ Wt,
                     int kshift, int total) {
  int idx = blockIdx.x*256 + threadIdx.x;
  if (idx >= total) return;
  int n = idx >> kshift;
  int k = idx & ((1 << kshift) - 1);
  Wt[idx] = f2b(W[(size_t)k*H + n]);
}

// ---------- layer-0 aggregation on F=128 channels: z = bf16(Â x) ----------
// one wave per node; lane owns 2 channels (4B/lane); gather unrolled by 4.
__global__ __launch_bounds__(1024) void aggregate0_k(
    const ushort* __restrict__ xs, const int* __restrict__ src,
    const int* __restrict__ rowptr, const float* __restrict__ dinv,
    ushort* __restrict__ z, int N_, int F_) {
  int t = threadIdx.x;
  int lane = t & 63, wv = t >> 6;
  int ch = lane * 2;
  for (int c = blockIdx.x*16 + wv; c < N_; c += gridDim.x*16) {
    float di = dinv[c];
    ushort2 sv = *(const ushort2*)(xs + (size_t)c*F_ + ch);
    float a0 = b2f(sv.x), b0 = b2f(sv.y);
    float a1=0.f,b1=0.f,a2=0.f,b2=0.f,a3=0.f,b3=0.f;
    int s = rowptr[c], e = rowptr[c+1];
    int j = s;
    for (; j + 4 <= e; j += 4) {
      int r0 = src[j], r1 = src[j+1], r2 = src[j+2], r3 = src[j+3];
      ushort2 v0 = *(const ushort2*)(xs + (size_t)r0*F_ + ch);
      ushort2 v1 = *(const ushort2*)(xs + (size_t)r1*F_ + ch);
      ushort2 v2 = *(const ushort2*)(xs + (size_t)r2*F_ + ch);
      ushort2 v3 = *(const ushort2*)(xs + (size_t)r3*F_ + ch);
      a0 += b2f(v0.x); b0 += b2f(v0.y);
      a1 += b2f(v1.x); b1 += b2f(v1.y);
      a2 += b2f(v2.x); b2 += b2f(v2.y);
      a3 += b2f(v3.x); b3 += b2f(v3.y);
    }
    for (; j < e; j++) {
      int r = src[j];
      ushort2 v = *(const ushort2*)(xs + (size_t)r*F_ + ch);
      a0 += b2f(v.x); b0 += b2f(v.y);
    }
    float sa = (a0+a1)+(a2+a3);
    float sb = (b0+b1)+(b2+b3);
    ushort2 o; o.x = f2b(sa*di); o.y = f2b(sb*di);
    *(ushort2*)(z + (size_t)c*F_ + ch) = o;
  }
}

// ---------- GEMM: acc = A[N][K] @ Wt^T, register double-buffered ----------
// MODE 0: y = bf16(dinv[row]*acc)          (layers 1,2; feeds aggregation)
// MODE 1: agg = acc + bias (fp32) + fused BN-stats partials  (layer 0)
template<int K, int MODE>
__global__ __launch_bounds__(256) void gemm_mfma_k(
    const ushort* __restrict__ A, const ushort* __restrict__ Wt,
    const float* __restrict__ dinv, const float* __restrict__ bias,
    ushort* __restrict__ y, float* __restrict__ agg, float* __restrict__ stats,
    int N_) {
  __shared__ float ls[2*H];
  int t = threadIdx.x;
  int lane = t & 63, w = t >> 6;
  int r0 = blockIdx.x * 64;
  int c0 = w * 64;
  int lr = lane & 15, lk = (lane >> 4) * 8;

  f32x4 acc[4][4];
#pragma unroll
  for (int m = 0; m < 4; m++)
#pragma unroll
    for (int n = 0; n < 4; n++) acc[m][n] = (f32x4)0.f;

  const ushort* Ap[4];
#pragma unroll
  for (int m = 0; m < 4; m++) {
    int row = r0 + m*16 + lr; if (row > N_-1) row = N_-1;
    Ap[m] = A + (size_t)row*K + lk;
  }
  const ushort* Wp[4];
#pragma unroll
  for (int n = 0; n < 4; n++) Wp[n] = Wt + (size_t)(c0 + n*16 + lr)*K + lk;

  const int NSTEP = K / 32;
  bf16x8 ac[4], bc[4], an[4], bn[4];
#pragma unroll
  for (int m = 0; m < 4; m++) ac[m] = *(const bf16x8*)(Ap[m]);
#pragma unroll
  for (int n = 0; n < 4; n++) bc[n] = *(const bf16x8*)(Wp[n]);

#pragma unroll
  for (int s = 0; s < NSTEP; s++) {
    if (s + 1 < NSTEP) {
      int k0 = (s + 1) * 32;
#pragma unroll
      for (int m = 0; m < 4; m++) an[m] = *(const bf16x8*)(Ap[m] + k0);
#pragma unroll
      for (int n = 0; n < 4; n++) bn[n] = *(const bf16x8*)(Wp[n] + k0);
    }
#pragma unroll
    for (int m = 0; m < 4; m++)
#pragma unroll
      for (int n = 0; n < 4; n++)
        acc[m][n] = __builtin_amdgcn_mfma_f32_16x16x32_bf16(ac[m], bc[n], acc[m][n], 0, 0, 0);
    if (s + 1 < NSTEP) {
#pragma unroll
      for (int m = 0; m < 4; m++) ac[m] = an[m];
#pragma unroll
      for (int n = 0; n < 4; n++) bc[n] = bn[n];
    }
  }

  int lrow = (lane >> 4) * 4;
  int lcol = lane & 15;

  if (MODE == 0) {
#pragma unroll
    for (int m = 0; m < 4; m++) {
#pragma unroll
      for (int r = 0; r < 4; r++) {
        int row = r0 + m*16 + lrow + r;
        if (row < N_) {
          float dv = dinv[row];
#pragma unroll
          for (int n = 0; n < 4; n++)
            y[(size_t)row*H + c0 + n*16 + lcol] = f2b(acc[m][n][r] * dv);
        }
      }
    }
  } else {
    ls[t] = 0.f; ls[t + H] = 0.f;
    __syncthreads();
    float bvn[4];
#pragma unroll
    for (int n = 0; n < 4; n++) bvn[n] = bias[c0 + n*16 + lcol];
    float sn[4] = {0.f,0.f,0.f,0.f}, qn[4] = {0.f,0.f,0.f,0.f};
#pragma unroll
    for (int m = 0; m < 4; m++) {
#pragma unroll
      for (int r = 0; r < 4; r++) {
        int row = r0 + m*16 + lrow + r;
        if (row < N_) {
#pragma unroll
          for (int n = 0; n < 4; n++) {
            float v = acc[m][n][r] + bvn[n];
            agg[(size_t)row*H + c0 + n*16 + lcol] = v;
            sn[n] += v; qn[n] = fmaf(v, v, qn[n]);
          }
        }
      }
    }
#pragma unroll
    for (int n = 0; n < 4; n++) {
      atomicAdd(&ls[c0 + n*16 + lcol], sn[n]);
      atomicAdd(&ls[H + c0 + n*16 + lcol], qn[n]);
    }
    __syncthreads();
    atomicAdd(&stats[t], ls[t]);
    atomicAdd(&stats[H + t], ls[H + t]);
  }
}

// ---------- aggregation + fused BN stats (layers 1,2) ----------
// 1024-thread blocks (16 waves) -> 4x fewer global stats atomics.
__global__ __launch_bounds__(1024) void aggregate_k(
    const ushort* __restrict__ y, const int* __restrict__ src,
    const int* __restrict__ rowptr, const float* __restrict__ dinv,
    const float* __restrict__ b, float* __restrict__ agg,
    float* __restrict__ stats, int N_) {
  __shared__ float ls[2*H];
  int t = threadIdx.x;
  if (t < 2*H) ls[t] = 0.f;
  __syncthreads();

  int lane = t & 63, wv = t >> 6;
  int ch = lane * 4;
  float4 bv = *(const float4*)(b + ch);

  float s0=0.f, s1=0.f, s2=0.f, s3=0.f;
  float q0=0.f, q1=0.f, q2=0.f, q3=0.f;

  for (int c = blockIdx.x*16 + wv; c < N_; c += gridDim.x*16) {
    float di = dinv[c];
    ushort4 sv = *(const ushort4*)(y + (size_t)c*H + ch);
    float a0x = b2f(sv.x), a0y = b2f(sv.y), a0z = b2f(sv.z), a0w = b2f(sv.w);
    float a1x=0.f,a1y=0.f,a1z=0.f,a1w=0.f;
    float a2x=0.f,a2y=0.f,a2z=0.f,a2w=0.f;
    float a3x=0.f,a3y=0.f,a3z=0.f,a3w=0.f;
    int s = rowptr[c], e = rowptr[c+1];
    int j = s;
    for (; j + 4 <= e; j += 4) {
      int r0 = src[j], r1 = src[j+1], r2 = src[j+2], r3 = src[j+3];
      ushort4 v0 = *(const ushort4*)(y + (size_t)r0*H + ch);
      ushort4 v1 = *(const ushort4*)(y + (size_t)r1*H + ch);
      ushort4 v2 = *(const ushort4*)(y + (size_t)r2*H + ch);
      ushort4 v3 = *(const ushort4*)(y + (size_t)r3*H + ch);
      a0x += b2f(v0.x); a0y += b2f(v0.y); a0z += b2f(v0.z); a0w += b2f(v0.w);
      a1x += b2f(v1.x); a1y += b2f(v1.y); a1z += b2f(v1.z); a1w += b2f(v1.w);
      a2x += b2f(v2.x); a2y += b2f(v2.y); a2z += b2f(v2.z); a2w += b2f(v2.w);
      a3x += b2f(v3.x); a3y += b2f(v3.y); a3z += b2f(v3.z); a3w += b2f(v3.w);
    }
    for (; j < e; j++) {
      int r = src[j];
      ushort4 v = *(const ushort4*)(y + (size_t)r*H + ch);
      a0x += b2f(v.x); a0y += b2f(v.y); a0z += b2f(v.z); a0w += b2f(v.w);
    }
    float ax = (a0x + a1x) + (a2x + a3x);
    float ay = (a0y + a1y) + (a2y + a3y);
    float az = (a0z + a1z) + (a2z + a3z);
    float aw = (a0w + a1w) + (a2w + a3w);
    float4 o;
    o.x = fmaf(ax, di, bv.x);
    o.y = fmaf(ay, di, bv.y);
    o.z = fmaf(az, di, bv.z);
    o.w = fmaf(aw, di, bv.w);
    *(float4*)(agg + (size_t)c*H + ch) = o;
    s0 += o.x; q0 = fmaf(o.x, o.x, q0);
    s1 += o.y; q1 = fmaf(o.y, o.y, q1);
    s2 += o.z; q2 = fmaf(o.z, o.z, q2);
    s3 += o.w; q3 = fmaf(o.w, o.w, q3);
  }

  atomicAdd(&ls[ch+0], s0); atomicAdd(&ls[H+ch+0], q0);
  atomicAdd(&ls[ch+1], s1); atomicAdd(&ls[H+ch+1], q1);
  atomicAdd(&ls[ch+2], s2); atomicAdd(&ls[H+ch+2], q2);
  atomicAdd(&ls[ch+3], s3); atomicAdd(&ls[H+ch+3], q3);
  __syncthreads();
  if (t < 2*H) atomicAdd(&stats[t], ls[t]);
}

// ---------- batch norm apply (bf16 in-place residual) ----------
__global__ void bn_apply_k(const float* __restrict__ agg, const float* __restrict__ stats,
                           const float* __restrict__ g, const float* __restrict__ beta,
                           ushort* __restrict__ hb, int N_, float invN, int residual) {
  int t = threadIdx.x;
  size_t idx = (size_t)blockIdx.x*H + t;
  float mu  = stats[t]*invN;
  float var = stats[H+t]*invN - mu*mu;
  float x = (agg[idx]-mu)*rsqrtf(var+EPS)*g[t] + beta[t];
  x = fmaxf(x, 0.f);
  float o = residual ? (b2f(hb[idx]) + x) : x;
  hb[idx] = f2b(o);
}

// ---------- pooling + MLP ----------
__global__ void pool_k(const ushort* __restrict__ hb, const int* __restrict__ gstart,
                       float* __restrict__ pooled) {
  int g = blockIdx.x, t = threadIdx.x;
  int s = gstart[g], e = gstart[g+1];
  float sum = 0.f;
  for (int n = s; n < e; n++) sum += b2f(hb[(size_t)n*H + t]);
  float cnt = fmaxf((float)(e - s), 1.f);
  pooled[(size_t)g*H + t] = sum/cnt + sum;
}

__global__ void mlp_k(const float* __restrict__ pooled, const float* __restrict__ mW1,
                      const float* __restrict__ mb1, const float* __restrict__ mW2,
                      const float* __restrict__ mb2, float* __restrict__ out) {
  int g = blockIdx.x, t = threadIdx.x; // 128 threads
  __shared__ float p[H];
  __shared__ float mid[128];
  p[t]       = pooled[(size_t)g*H + t];
  p[t+128]   = pooled[(size_t)g*H + t + 128];
  __syncthreads();
  float a = mb1[t];
  for (int k = 0; k < H; k++) a = fmaf(p[k], mW1[(size_t)k*128 + t], a);
  a = fmaxf(a, 0.f);
  mid[t] = a * mW2[t];
  __syncthreads();
  for (int off = 64; off > 0; off >>= 1) {
    if (t < off) mid[t] += mid[t+off];
    __syncthreads();
  }
  if (t == 0) out[g] = mid[0] + mb2[0];
}

extern "C" void kernel_launch(void* const* d_in, const int* in_sizes, int n_in,
                              void* d_out, int out_size, void* d_ws, size_t ws_size,
                              hipStream_t stream) {
  const float* x        = (const float*)d_in[0];
  const void*  ei_raw   = d_in[1];
  const void*  batch_raw= d_in[2];
  const float* W0 = (const float*)d_in[3];
  const float* b0 = (const float*)d_in[4];
  const float* g0 = (const float*)d_in[5];
  const float* be0= (const float*)d_in[6];
  const float* W1 = (const float*)d_in[7];
  const float* b1 = (const float*)d_in[8];
  const float* g1 = (const float*)d_in[9];
  const float* be1= (const float*)d_in[10];
  const float* W2 = (const float*)d_in[11];
  const float* b2 = (const float*)d_in[12];
  const float* g2 = (const float*)d_in[13];
  const float* be2= (const float*)d_in[14];
  const float* mW1= (const float*)d_in[15];
  const float* mb1= (const float*)d_in[16];
  const float* mW2= (const float*)d_in[17];
  const float* mb2= (const float*)d_in[18];
  float* out = (float*)d_out;

  int N_ = in_sizes[2];
  int E_ = in_sizes[1] / 2;
  int F_ = in_sizes[0] / N_;
  int G_ = out_size;

  char* ws = (char*)d_ws;
  size_t off = 0;
  auto alloc = [&](size_t bytes) -> void* {
    void* p = ws + off;
    off = (off + bytes + 255) & ~(size_t)255;
    return p;
  };
  float*  agg    = (float*) alloc((size_t)N_*H*4);
  ushort* y      = (ushort*)alloc((size_t)N_*H*2);
  ushort* hb     = (ushort*)alloc((size_t)N_*H*2);
  ushort* xs     = (ushort*)alloc((size_t)N_*F_*2);
  ushort* z      = (ushort*)alloc((size_t)N_*F_*2);
  ushort* Wt0    = (ushort*)alloc((size_t)F_*H*2);
  ushort* Wt1    = (ushort*)alloc((size_t)H*H*2);
  ushort* Wt2    = (ushort*)alloc((size_t)H*H*2);
  int*    eidx   = (int*)   alloc((size_t)2*E_*4);
  int*    csr    = (int*)   alloc((size_t)E_*4);
  int*    batch  = (int*)   alloc((size_t)N_*4);
  int*    cnt    = (int*)   alloc((size_t)N_*4);
  int*    fill   = (int*)   alloc((size_t)N_*4);
  int*    rowptr = (int*)   alloc((size_t)(N_+1)*4);
  float*  dinv   = (float*) alloc((size_t)N_*4);
  float*  stats  = (float*) alloc(2*H*4);
  int*    gstart = (int*)   alloc((size_t)(G_+1)*4);
  float*  pooled = (float*) alloc((size_t)G_*H*4);
  int*    flag   = (int*)   alloc(4);

  // index preprocessing
  detect_i64_k<<<1, 64, 0, stream>>>((const int*)ei_raw, flag);
  convert_idx_k<<<(2*E_+255)/256, 256, 0, stream>>>(ei_raw, flag, eidx, 2*E_);
  convert_idx_k<<<(N_+255)/256, 256, 0, stream>>>(batch_raw, flag, batch, N_);
  hipMemsetAsync(cnt, 0, (size_t)N_*4, stream);
  hipMemsetAsync(fill, 0, (size_t)N_*4, stream);
  count_edges_k<<<(E_+255)/256, 256, 0, stream>>>(eidx + E_, cnt, E_);
  dinv_k<<<(N_+255)/256, 256, 0, stream>>>(cnt, dinv, N_);
  scan_k<<<1, 1024, 0, stream>>>(cnt, rowptr, N_);
  fill_csr_k<<<(E_+255)/256, 256, 0, stream>>>(eidx, eidx + E_, rowptr, fill, csr, E_);
  graph_starts_k<<<(G_+256)/256, 256, 0, stream>>>(batch, gstart, N_, G_);

  // converts
  int ksh0 = 31 - __builtin_clz(F_);
  xs_k<<<((N_*F_/4)+255)/256, 256, 0, stream>>>(x, dinv, xs, N_*F_/4, F_);
  wt_k<<<((F_*H)+255)/256, 256, 0, stream>>>(W0, Wt0, ksh0, F_*H);
  wt_k<<<((H*H)+255)/256, 256, 0, stream>>>(W1, Wt1, 8, H*H);
  wt_k<<<((H*H)+255)/256, 256, 0, stream>>>(W2, Wt2, 8, H*H);

  float invN = 1.0f / (float)N_;
  int nb = (N_ + 63) / 64;

  // ---- layer 0: aggregate (F-dim) -> GEMM(+bias,+stats) -> BN ----
  aggregate0_k<<<512, 1024, 0, stream>>>(xs, csr, rowptr, dinv, z, N_, F_);
  hipMemsetAsync(stats, 0, 2*H*4, stream);
  if (F_ == 128)
    gemm_mfma_k<128,1><<<nb, 256, 0, stream>>>(z, Wt0, dinv, b0, y, agg, stats, N_);
  else
    gemm_mfma_k<256,1><<<nb, 256, 0, stream>>>(z, Wt0, dinv, b0, y, agg, stats, N_);
  bn_apply_k<<<N_, H, 0, stream>>>(agg, stats, g0, be0, hb, N_, invN, 0);

  // ---- layers 1,2: GEMM(xdinv) -> aggregate(+bias,+stats) -> BN ----
  const float* bs[2]  = {b1, b2};
  const float* gs[2]  = {g1, g2};
  const float* bes[2] = {be1, be2};
  const ushort* Wts[2] = {Wt1, Wt2};
  for (int L = 0; L < 2; L++) {
    gemm_mfma_k<256,0><<<nb, 256, 0, stream>>>(hb, Wts[L], dinv, bs[L], y, agg, stats, N_);
    hipMemsetAsync(stats, 0, 2*H*4, stream);
    aggregate_k<<<512, 1024, 0, stream>>>(y, csr, rowptr, dinv, bs[L], agg, stats, N_);
    bn_apply_k<<<N_, H, 0, stream>>>(agg, stats, gs[L], bes[L], hb, N_, invN, 1);
  }

  pool_k<<<G_, H, 0, stream>>>(hb, gstart, pooled);
  mlp_k<<<G_, 128, 0, stream>>>(pooled, mW1, mb1, mW2, mb2, out);
}

// Round 5
// 534.293 us; speedup vs baseline: 5.6208x; 1.1802x over previous
//
#include <hip/hip_runtime.h>
#include <math.h>

#define H 256
#define EPS 1e-5f

typedef __attribute__((ext_vector_type(8))) short bf16x8;
typedef __attribute__((ext_vector_type(4))) float f32x4;

__device__ inline ushort f2b(float f) {
  union { float f; unsigned u; } v; v.f = f;
  unsigned r = v.u + 0x7FFF + ((v.u >> 16) & 1);
  return (ushort)(r >> 16);
}
__device__ inline float b2f(ushort u) {
  union { unsigned u; float f; } v; v.u = ((unsigned)u) << 16;
  return v.f;
}

// ---------- index dtype detection & conversion ----------
__global__ void detect_i64_k(const int* __restrict__ w, int* __restrict__ flag) {
  if (threadIdx.x == 0 && blockIdx.x == 0) {
    int all0 = 1;
    for (int k = 0; k < 64; k++) if (w[2*k+1] != 0) { all0 = 0; break; }
    *flag = all0;
  }
}

__global__ void convert_idx_k(const void* __restrict__ raw, const int* __restrict__ flag,
                              int* __restrict__ out, int n) {
  int i = blockIdx.x*256 + threadIdx.x;
  if (i >= n) return;
  if (*flag) out[i] = (int)((const long long*)raw)[i];
  else       out[i] = ((const int*)raw)[i];
}

// ---------- graph preprocessing ----------
__global__ void count_edges_k(const int* __restrict__ col, int* __restrict__ cnt, int E_) {
  int e = blockIdx.x*256 + threadIdx.x;
  if (e < E_) atomicAdd(&cnt[col[e]], 1);
}

__global__ void dinv_k(const int* __restrict__ cnt, float* __restrict__ dinv, int N_) {
  int i = blockIdx.x*256 + threadIdx.x;
  if (i < N_) dinv[i] = rsqrtf((float)cnt[i] + 1.0f);
}

// ---------- hierarchical exclusive scan: rowptr[0..N] ----------
// phase 1: 1024 elems/block (256 thr x 4), block-local exclusive scan + bsum
__global__ void scan1_k(const int* __restrict__ cnt, int* __restrict__ rowptr,
                        int* __restrict__ bsum, int N_) {
  __shared__ int sh[256];
  int t = threadIdx.x;
  int i0 = blockIdx.x*1024 + t*4;
  int v0=0,v1=0,v2=0,v3=0;
  if (i0+0 < N_) v0 = cnt[i0+0];
  if (i0+1 < N_) v1 = cnt[i0+1];
  if (i0+2 < N_) v2 = cnt[i0+2];
  if (i0+3 < N_) v3 = cnt[i0+3];
  sh[t] = v0+v1+v2+v3;
  __syncthreads();
  for (int off = 1; off < 256; off <<= 1) {
    int x = (t >= off) ? sh[t-off] : 0;
    __syncthreads();
    sh[t] += x;
    __syncthreads();
  }
  int excl = (t == 0) ? 0 : sh[t-1];
  if (i0+0 < N_) rowptr[i0+0] = excl;
  if (i0+1 < N_) rowptr[i0+1] = excl+v0;
  if (i0+2 < N_) rowptr[i0+2] = excl+v0+v1;
  if (i0+3 < N_) rowptr[i0+3] = excl+v0+v1+v2;
  if (t == 255) bsum[blockIdx.x] = sh[255];
}

// phase 2: one wave scans block sums in-place to exclusive offsets
__global__ void scan2_k(int* __restrict__ bsum, int* __restrict__ rowptr,
                        int nb, int N_) {
  int lane = threadIdx.x; // 64 threads
  int carry = 0;
  for (int base = 0; base < nb; base += 64) {
    int i = base + lane;
    int orig = (i < nb) ? bsum[i] : 0;
    int v = orig;
    for (int off = 1; off < 64; off <<= 1) {
      int u = __shfl_up(v, off);
      if (lane >= off) v += u;
    }
    if (i < nb) bsum[i] = carry + v - orig; // exclusive
    carry += __shfl(v, 63);
  }
  if (lane == 0) rowptr[N_] = carry;
}

// phase 3: add block offsets
__global__ void scan3_k(int* __restrict__ rowptr, const int* __restrict__ bsum, int N_) {
  int off = bsum[blockIdx.x];
  int i = blockIdx.x*1024 + threadIdx.x*4;
#pragma unroll
  for (int k = 0; k < 4; k++) if (i+k < N_) rowptr[i+k] += off;
}

__global__ void fill_csr_k(const int* __restrict__ row, const int* __restrict__ col,
                           const int* __restrict__ rowptr, int* __restrict__ fill,
                           int* __restrict__ src, int E_) {
  int e = blockIdx.x*256 + threadIdx.x;
  if (e < E_) {
    int c = col[e];
    int p = rowptr[c] + atomicAdd(&fill[c], 1);
    src[p] = row[e];
  }
}

__global__ void graph_starts_k(const int* __restrict__ batch, int* __restrict__ gstart,
                               int N_, int G_) {
  int g = blockIdx.x*256 + threadIdx.x;
  if (g > G_) return;
  int lo = 0, hi = N_;
  while (lo < hi) { int m = (lo+hi) >> 1; if (batch[m] < g) lo = m+1; else hi = m; }
  gstart[g] = lo;
}

// ---------- xs[r][f] = bf16(dinv[r] * x[r][f]) ----------
__global__ void xs_k(const float* __restrict__ x, const float* __restrict__ dinv,
                     ushort* __restrict__ xs, int n4, int F_) {
  int i = blockIdx.x*256 + threadIdx.x;
  if (i >= n4) return;
  int row = (i << 2) / F_;
  float dv = dinv[row];
  float4 v = ((const float4*)x)[i];
  ushort4 o;
  o.x = f2b(v.x*dv); o.y = f2b(v.y*dv); o.z = f2b(v.z*dv); o.w = f2b(v.w*dv);
  ((ushort4*)xs)[i] = o;
}

// Wt[n][k] = bf16(W[k][n]);   idx = n*K + k
__global__ void wt_k(const float* __restrict__ W, ushort* __restrict__ Wt,
                     int kshift, int total) {
  int idx = blockIdx.x*256 + threadIdx.x;
  if (idx >= total) return;
  int n = idx >> kshift;
  int k = idx & ((1 << kshift) - 1);
  Wt[idx] = f2b(W[(size_t)k*H + n]);
}

// ---------- layer-0 aggregation on F channels: z = bf16(Â x) ----------
__global__ __launch_bounds__(1024) void aggregate0_k(
    const ushort* __restrict__ xs, const int* __restrict__ src,
    const int* __restrict__ rowptr, const float* __restrict__ dinv,
    ushort* __restrict__ z, int N_, int F_) {
  int t = threadIdx.x;
  int lane = t & 63, wv = t >> 6;
  int ch = lane * 2;
  for (int c = blockIdx.x*16 + wv; c < N_; c += gridDim.x*16) {
    float di = dinv[c];
    ushort2 sv = *(const ushort2*)(xs + (size_t)c*F_ + ch);
    float a0 = b2f(sv.x), b0 = b2f(sv.y);
    float a1=0.f,b1=0.f,a2=0.f,b2=0.f,a3=0.f,b3=0.f;
    int s = rowptr[c], e = rowptr[c+1];
    int j = s;
    for (; j + 8 <= e; j += 8) {
      int r0 = src[j],   r1 = src[j+1], r2 = src[j+2], r3 = src[j+3];
      int r4 = src[j+4], r5 = src[j+5], r6 = src[j+6], r7 = src[j+7];
      ushort2 v0 = *(const ushort2*)(xs + (size_t)r0*F_ + ch);
      ushort2 v1 = *(const ushort2*)(xs + (size_t)r1*F_ + ch);
      ushort2 v2 = *(const ushort2*)(xs + (size_t)r2*F_ + ch);
      ushort2 v3 = *(const ushort2*)(xs + (size_t)r3*F_ + ch);
      ushort2 v4 = *(const ushort2*)(xs + (size_t)r4*F_ + ch);
      ushort2 v5 = *(const ushort2*)(xs + (size_t)r5*F_ + ch);
      ushort2 v6 = *(const ushort2*)(xs + (size_t)r6*F_ + ch);
      ushort2 v7 = *(const ushort2*)(xs + (size_t)r7*F_ + ch);
      a0 += b2f(v0.x); b0 += b2f(v0.y);
      a1 += b2f(v1.x); b1 += b2f(v1.y);
      a2 += b2f(v2.x); b2 += b2f(v2.y);
      a3 += b2f(v3.x); b3 += b2f(v3.y);
      a0 += b2f(v4.x); b0 += b2f(v4.y);
      a1 += b2f(v5.x); b1 += b2f(v5.y);
      a2 += b2f(v6.x); b2 += b2f(v6.y);
      a3 += b2f(v7.x); b3 += b2f(v7.y);
    }
    for (; j + 4 <= e; j += 4) {
      int r0 = src[j], r1 = src[j+1], r2 = src[j+2], r3 = src[j+3];
      ushort2 v0 = *(const ushort2*)(xs + (size_t)r0*F_ + ch);
      ushort2 v1 = *(const ushort2*)(xs + (size_t)r1*F_ + ch);
      ushort2 v2 = *(const ushort2*)(xs + (size_t)r2*F_ + ch);
      ushort2 v3 = *(const ushort2*)(xs + (size_t)r3*F_ + ch);
      a0 += b2f(v0.x); b0 += b2f(v0.y);
      a1 += b2f(v1.x); b1 += b2f(v1.y);
      a2 += b2f(v2.x); b2 += b2f(v2.y);
      a3 += b2f(v3.x); b3 += b2f(v3.y);
    }
    for (; j < e; j++) {
      int r = src[j];
      ushort2 v = *(const ushort2*)(xs + (size_t)r*F_ + ch);
      a0 += b2f(v.x); b0 += b2f(v.y);
    }
    float sa = (a0+a1)+(a2+a3);
    float sb = (b0+b1)+(b2+b3);
    ushort2 o; o.x = f2b(sa*di); o.y = f2b(sb*di);
    *(ushort2*)(z + (size_t)c*F_ + ch) = o;
  }
}

// ---------- GEMM: acc = A[N][K] @ Wt^T, register double-buffered ----------
// MODE 0: y = bf16(dinv[row]*acc)            (layers 1,2; feeds aggregation)
// MODE 1: aggb = bf16(acc + bias) + fused BN-stats partials  (layer 0)
template<int K, int MODE>
__global__ __launch_bounds__(256) void gemm_mfma_k(
    const ushort* __restrict__ A, const ushort* __restrict__ Wt,
    const float* __restrict__ dinv, const float* __restrict__ bias,
    ushort* __restrict__ y, ushort* __restrict__ aggb, float* __restrict__ stats,
    int N_) {
  __shared__ float ls[2*H];
  int t = threadIdx.x;
  int lane = t & 63, w = t >> 6;
  int r0 = blockIdx.x * 64;
  int c0 = w * 64;
  int lr = lane & 15, lk = (lane >> 4) * 8;

  f32x4 acc[4][4];
#pragma unroll
  for (int m = 0; m < 4; m++)
#pragma unroll
    for (int n = 0; n < 4; n++) acc[m][n] = (f32x4)0.f;

  const ushort* Ap[4];
#pragma unroll
  for (int m = 0; m < 4; m++) {
    int row = r0 + m*16 + lr; if (row > N_-1) row = N_-1;
    Ap[m] = A + (size_t)row*K + lk;
  }
  const ushort* Wp[4];
#pragma unroll
  for (int n = 0; n < 4; n++) Wp[n] = Wt + (size_t)(c0 + n*16 + lr)*K + lk;

  const int NSTEP = K / 32;
  bf16x8 ac[4], bc[4], an[4], bn[4];
#pragma unroll
  for (int m = 0; m < 4; m++) ac[m] = *(const bf16x8*)(Ap[m]);
#pragma unroll
  for (int n = 0; n < 4; n++) bc[n] = *(const bf16x8*)(Wp[n]);

#pragma unroll
  for (int s = 0; s < NSTEP; s++) {
    if (s + 1 < NSTEP) {
      int k0 = (s + 1) * 32;
#pragma unroll
      for (int m = 0; m < 4; m++) an[m] = *(const bf16x8*)(Ap[m] + k0);
#pragma unroll
      for (int n = 0; n < 4; n++) bn[n] = *(const bf16x8*)(Wp[n] + k0);
    }
#pragma unroll
    for (int m = 0; m < 4; m++)
#pragma unroll
      for (int n = 0; n < 4; n++)
        acc[m][n] = __builtin_amdgcn_mfma_f32_16x16x32_bf16(ac[m], bc[n], acc[m][n], 0, 0, 0);
    if (s + 1 < NSTEP) {
#pragma unroll
      for (int m = 0; m < 4; m++) ac[m] = an[m];
#pragma unroll
      for (int n = 0; n < 4; n++) bc[n] = bn[n];
    }
  }

  int lrow = (lane >> 4) * 4;
  int lcol = lane & 15;

  if (MODE == 0) {
#pragma unroll
    for (int m = 0; m < 4; m++) {
#pragma unroll
      for (int r = 0; r < 4; r++) {
        int row = r0 + m*16 + lrow + r;
        if (row < N_) {
          float dv = dinv[row];
#pragma unroll
          for (int n = 0; n < 4; n++)
            y[(size_t)row*H + c0 + n*16 + lcol] = f2b(acc[m][n][r] * dv);
        }
      }
    }
  } else {
    ls[t] = 0.f; ls[t + H] = 0.f;
    __syncthreads();
    float bvn[4];
#pragma unroll
    for (int n = 0; n < 4; n++) bvn[n] = bias[c0 + n*16 + lcol];
    float sn[4] = {0.f,0.f,0.f,0.f}, qn[4] = {0.f,0.f,0.f,0.f};
#pragma unroll
    for (int m = 0; m < 4; m++) {
#pragma unroll
      for (int r = 0; r < 4; r++) {
        int row = r0 + m*16 + lrow + r;
        if (row < N_) {
#pragma unroll
          for (int n = 0; n < 4; n++) {
            float v = acc[m][n][r] + bvn[n];
            aggb[(size_t)row*H + c0 + n*16 + lcol] = f2b(v);
            sn[n] += v; qn[n] = fmaf(v, v, qn[n]);
          }
        }
      }
    }
#pragma unroll
    for (int n = 0; n < 4; n++) {
      atomicAdd(&ls[c0 + n*16 + lcol], sn[n]);
      atomicAdd(&ls[H + c0 + n*16 + lcol], qn[n]);
    }
    __syncthreads();
    atomicAdd(&stats[t], ls[t]);
    atomicAdd(&stats[H + t], ls[H + t]);
  }
}

// ---------- aggregation + fused BN stats (layers 1,2) ----------
__global__ __launch_bounds__(1024) void aggregate_k(
    const ushort* __restrict__ y, const int* __restrict__ src,
    const int* __restrict__ rowptr, const float* __restrict__ dinv,
    const float* __restrict__ b, ushort* __restrict__ aggb,
    float* __restrict__ stats, int N_) {
  __shared__ float ls[2*H];
  int t = threadIdx.x;
  if (t < 2*H) ls[t] = 0.f;
  __syncthreads();

  int lane = t & 63, wv = t >> 6;
  int ch = lane * 4;
  float4 bv = *(const float4*)(b + ch);

  float s0=0.f, s1=0.f, s2=0.f, s3=0.f;
  float q0=0.f, q1=0.f, q2=0.f, q3=0.f;

  for (int c = blockIdx.x*16 + wv; c < N_; c += gridDim.x*16) {
    float di = dinv[c];
    ushort4 sv = *(const ushort4*)(y + (size_t)c*H + ch);
    float a0x = b2f(sv.x), a0y = b2f(sv.y), a0z = b2f(sv.z), a0w = b2f(sv.w);
    float a1x=0.f,a1y=0.f,a1z=0.f,a1w=0.f;
    float a2x=0.f,a2y=0.f,a2z=0.f,a2w=0.f;
    float a3x=0.f,a3y=0.f,a3z=0.f,a3w=0.f;
    int s = rowptr[c], e = rowptr[c+1];
    int j = s;
    for (; j + 8 <= e; j += 8) {
      int r0 = src[j],   r1 = src[j+1], r2 = src[j+2], r3 = src[j+3];
      int r4 = src[j+4], r5 = src[j+5], r6 = src[j+6], r7 = src[j+7];
      ushort4 v0 = *(const ushort4*)(y + (size_t)r0*H + ch);
      ushort4 v1 = *(const ushort4*)(y + (size_t)r1*H + ch);
      ushort4 v2 = *(const ushort4*)(y + (size_t)r2*H + ch);
      ushort4 v3 = *(const ushort4*)(y + (size_t)r3*H + ch);
      ushort4 v4 = *(const ushort4*)(y + (size_t)r4*H + ch);
      ushort4 v5 = *(const ushort4*)(y + (size_t)r5*H + ch);
      ushort4 v6 = *(const ushort4*)(y + (size_t)r6*H + ch);
      ushort4 v7 = *(const ushort4*)(y + (size_t)r7*H + ch);
      a0x += b2f(v0.x); a0y += b2f(v0.y); a0z += b2f(v0.z); a0w += b2f(v0.w);
      a1x += b2f(v1.x); a1y += b2f(v1.y); a1z += b2f(v1.z); a1w += b2f(v1.w);
      a2x += b2f(v2.x); a2y += b2f(v2.y); a2z += b2f(v2.z); a2w += b2f(v2.w);
      a3x += b2f(v3.x); a3y += b2f(v3.y); a3z += b2f(v3.z); a3w += b2f(v3.w);
      a0x += b2f(v4.x); a0y += b2f(v4.y); a0z += b2f(v4.z); a0w += b2f(v4.w);
      a1x += b2f(v5.x); a1y += b2f(v5.y); a1z += b2f(v5.z); a1w += b2f(v5.w);
      a2x += b2f(v6.x); a2y += b2f(v6.y); a2z += b2f(v6.z); a2w += b2f(v6.w);
      a3x += b2f(v7.x); a3y += b2f(v7.y); a3z += b2f(v7.z); a3w += b2f(v7.w);
    }
    for (; j + 4 <= e; j += 4) {
      int r0 = src[j], r1 = src[j+1], r2 = src[j+2], r3 = src[j+3];
      ushort4 v0 = *(const ushort4*)(y + (size_t)r0*H + ch);
      ushort4 v1 = *(const ushort4*)(y + (size_t)r1*H + ch);
      ushort4 v2 = *(const ushort4*)(y + (size_t)r2*H + ch);
      ushort4 v3 = *(const ushort4*)(y + (size_t)r3*H + ch);
      a0x += b2f(v0.x); a0y += b2f(v0.y); a0z += b2f(v0.z); a0w += b2f(v0.w);
      a1x += b2f(v1.x); a1y += b2f(v1.y); a1z += b2f(v1.z); a1w += b2f(v1.w);
      a2x += b2f(v2.x); a2y += b2f(v2.y); a2z += b2f(v2.z); a2w += b2f(v2.w);
      a3x += b2f(v3.x); a3y += b2f(v3.y); a3z += b2f(v3.z); a3w += b2f(v3.w);
    }
    for (; j < e; j++) {
      int r = src[j];
      ushort4 v = *(const ushort4*)(y + (size_t)r*H + ch);
      a0x += b2f(v.x); a0y += b2f(v.y); a0z += b2f(v.z); a0w += b2f(v.w);
    }
    float ax = (a0x + a1x) + (a2x + a3x);
    float ay = (a0y + a1y) + (a2y + a3y);
    float az = (a0z + a1z) + (a2z + a3z);
    float aw = (a0w + a1w) + (a2w + a3w);
    float ox = fmaf(ax, di, bv.x);
    float oy = fmaf(ay, di, bv.y);
    float oz = fmaf(az, di, bv.z);
    float ow = fmaf(aw, di, bv.w);
    ushort4 ob; ob.x = f2b(ox); ob.y = f2b(oy); ob.z = f2b(oz); ob.w = f2b(ow);
    *(ushort4*)(aggb + (size_t)c*H + ch) = ob;
    s0 += ox; q0 = fmaf(ox, ox, q0);
    s1 += oy; q1 = fmaf(oy, oy, q1);
    s2 += oz; q2 = fmaf(oz, oz, q2);
    s3 += ow; q3 = fmaf(ow, ow, q3);
  }

  atomicAdd(&ls[ch+0], s0); atomicAdd(&ls[H+ch+0], q0);
  atomicAdd(&ls[ch+1], s1); atomicAdd(&ls[H+ch+1], q1);
  atomicAdd(&ls[ch+2], s2); atomicAdd(&ls[H+ch+2], q2);
  atomicAdd(&ls[ch+3], s3); atomicAdd(&ls[H+ch+3], q3);
  __syncthreads();
  if (t < 2*H) atomicAdd(&stats[t], ls[t]);
}

// ---------- batch norm apply (vectorized, bf16 agg + bf16 residual) ----------
__global__ __launch_bounds__(256) void bn_apply_k(
    const ushort* __restrict__ aggb, const float* __restrict__ stats,
    const float* __restrict__ g, const float* __restrict__ beta,
    ushort* __restrict__ hb, int total4, float invN, int residual) {
  for (int i = blockIdx.x*256 + threadIdx.x; i < total4; i += gridDim.x*256) {
    int ch = (i << 2) & (H-1);
    ushort4 v = ((const ushort4*)aggb)[i];
    float sc[4], sh[4];
#pragma unroll
    for (int k = 0; k < 4; k++) {
      float mu  = stats[ch+k]*invN;
      float var = stats[H+ch+k]*invN - mu*mu;
      float s = g[ch+k]*rsqrtf(var+EPS);
      sc[k] = s; sh[k] = beta[ch+k] - mu*s;
    }
    float x0 = fmaxf(fmaf(b2f(v.x), sc[0], sh[0]), 0.f);
    float x1 = fmaxf(fmaf(b2f(v.y), sc[1], sh[1]), 0.f);
    float x2 = fmaxf(fmaf(b2f(v.z), sc[2], sh[2]), 0.f);
    float x3 = fmaxf(fmaf(b2f(v.w), sc[3], sh[3]), 0.f);
    if (residual) {
      ushort4 hv = ((const ushort4*)hb)[i];
      x0 += b2f(hv.x); x1 += b2f(hv.y); x2 += b2f(hv.z); x3 += b2f(hv.w);
    }
    ushort4 o; o.x = f2b(x0); o.y = f2b(x1); o.z = f2b(x2); o.w = f2b(x3);
    ((ushort4*)hb)[i] = o;
  }
}

// ---------- pooling + MLP ----------
__global__ void pool_k(const ushort* __restrict__ hb, const int* __restrict__ gstart,
                       float* __restrict__ pooled) {
  int g = blockIdx.x, t = threadIdx.x;
  int s = gstart[g], e = gstart[g+1];
  float sum = 0.f;
  for (int n = s; n < e; n++) sum += b2f(hb[(size_t)n*H + t]);
  float cnt = fmaxf((float)(e - s), 1.f);
  pooled[(size_t)g*H + t] = sum/cnt + sum;
}

__global__ void mlp_k(const float* __restrict__ pooled, const float* __restrict__ mW1,
                      const float* __restrict__ mb1, const float* __restrict__ mW2,
                      const float* __restrict__ mb2, float* __restrict__ out) {
  int g = blockIdx.x, t = threadIdx.x; // 128 threads
  __shared__ float p[H];
  __shared__ float mid[128];
  p[t]       = pooled[(size_t)g*H + t];
  p[t+128]   = pooled[(size_t)g*H + t + 128];
  __syncthreads();
  float a = mb1[t];
  for (int k = 0; k < H; k++) a = fmaf(p[k], mW1[(size_t)k*128 + t], a);
  a = fmaxf(a, 0.f);
  mid[t] = a * mW2[t];
  __syncthreads();
  for (int off = 64; off > 0; off >>= 1) {
    if (t < off) mid[t] += mid[t+off];
    __syncthreads();
  }
  if (t == 0) out[g] = mid[0] + mb2[0];
}

extern "C" void kernel_launch(void* const* d_in, const int* in_sizes, int n_in,
                              void* d_out, int out_size, void* d_ws, size_t ws_size,
                              hipStream_t stream) {
  const float* x        = (const float*)d_in[0];
  const void*  ei_raw   = d_in[1];
  const void*  batch_raw= d_in[2];
  const float* W0 = (const float*)d_in[3];
  const float* b0 = (const float*)d_in[4];
  const float* g0 = (const float*)d_in[5];
  const float* be0= (const float*)d_in[6];
  const float* W1 = (const float*)d_in[7];
  const float* b1 = (const float*)d_in[8];
  const float* g1 = (const float*)d_in[9];
  const float* be1= (const float*)d_in[10];
  const float* W2 = (const float*)d_in[11];
  const float* b2 = (const float*)d_in[12];
  const float* g2 = (const float*)d_in[13];
  const float* be2= (const float*)d_in[14];
  const float* mW1= (const float*)d_in[15];
  const float* mb1= (const float*)d_in[16];
  const float* mW2= (const float*)d_in[17];
  const float* mb2= (const float*)d_in[18];
  float* out = (float*)d_out;

  int N_ = in_sizes[2];
  int E_ = in_sizes[1] / 2;
  int F_ = in_sizes[0] / N_;
  int G_ = out_size;

  char* ws = (char*)d_ws;
  size_t off = 0;
  auto alloc = [&](size_t bytes) -> void* {
    void* p = ws + off;
    off = (off + bytes + 255) & ~(size_t)255;
    return p;
  };
  ushort* aggb   = (ushort*)alloc((size_t)N_*H*2);
  ushort* y      = (ushort*)alloc((size_t)N_*H*2);
  ushort* hb     = (ushort*)alloc((size_t)N_*H*2);
  ushort* xs     = (ushort*)alloc((size_t)N_*F_*2);
  ushort* z      = (ushort*)alloc((size_t)N_*F_*2);
  ushort* Wt0    = (ushort*)alloc((size_t)F_*H*2);
  ushort* Wt1    = (ushort*)alloc((size_t)H*H*2);
  ushort* Wt2    = (ushort*)alloc((size_t)H*H*2);
  int*    eidx   = (int*)   alloc((size_t)2*E_*4);
  int*    csr    = (int*)   alloc((size_t)E_*4);
  int*    batch  = (int*)   alloc((size_t)N_*4);
  int*    cnt    = (int*)   alloc((size_t)N_*4);
  int*    fill   = (int*)   alloc((size_t)N_*4);
  int*    rowptr = (int*)   alloc((size_t)(N_+1)*4);
  int*    bsum   = (int*)   alloc((size_t)((N_+1023)/1024 + 64)*4);
  float*  dinv   = (float*) alloc((size_t)N_*4);
  float*  stats  = (float*) alloc(2*H*4);
  int*    gstart = (int*)   alloc((size_t)(G_+1)*4);
  float*  pooled = (float*) alloc((size_t)G_*H*4);
  int*    flag   = (int*)   alloc(4);

  // index preprocessing
  detect_i64_k<<<1, 64, 0, stream>>>((const int*)ei_raw, flag);
  convert_idx_k<<<(2*E_+255)/256, 256, 0, stream>>>(ei_raw, flag, eidx, 2*E_);
  convert_idx_k<<<(N_+255)/256, 256, 0, stream>>>(batch_raw, flag, batch, N_);
  hipMemsetAsync(cnt, 0, (size_t)N_*4, stream);
  hipMemsetAsync(fill, 0, (size_t)N_*4, stream);
  count_edges_k<<<(E_+255)/256, 256, 0, stream>>>(eidx + E_, cnt, E_);
  dinv_k<<<(N_+255)/256, 256, 0, stream>>>(cnt, dinv, N_);
  int nb1 = (N_ + 1023) / 1024;
  scan1_k<<<nb1, 256, 0, stream>>>(cnt, rowptr, bsum, N_);
  scan2_k<<<1, 64, 0, stream>>>(bsum, rowptr, nb1, N_);
  scan3_k<<<nb1, 256, 0, stream>>>(rowptr, bsum, N_);
  fill_csr_k<<<(E_+255)/256, 256, 0, stream>>>(eidx, eidx + E_, rowptr, fill, csr, E_);
  graph_starts_k<<<(G_+256)/256, 256, 0, stream>>>(batch, gstart, N_, G_);

  // converts
  int ksh0 = 31 - __builtin_clz(F_);
  xs_k<<<((N_*F_/4)+255)/256, 256, 0, stream>>>(x, dinv, xs, N_*F_/4, F_);
  wt_k<<<((F_*H)+255)/256, 256, 0, stream>>>(W0, Wt0, ksh0, F_*H);
  wt_k<<<((H*H)+255)/256, 256, 0, stream>>>(W1, Wt1, 8, H*H);
  wt_k<<<((H*H)+255)/256, 256, 0, stream>>>(W2, Wt2, 8, H*H);

  float invN = 1.0f / (float)N_;
  int nb = (N_ + 63) / 64;
  int total4 = N_*H/4;

  // ---- layer 0: aggregate (F-dim) -> GEMM(+bias,+stats) -> BN ----
  aggregate0_k<<<512, 1024, 0, stream>>>(xs, csr, rowptr, dinv, z, N_, F_);
  hipMemsetAsync(stats, 0, 2*H*4, stream);
  if (F_ == 128)
    gemm_mfma_k<128,1><<<nb, 256, 0, stream>>>(z, Wt0, dinv, b0, y, aggb, stats, N_);
  else
    gemm_mfma_k<256,1><<<nb, 256, 0, stream>>>(z, Wt0, dinv, b0, y, aggb, stats, N_);
  bn_apply_k<<<2048, 256, 0, stream>>>(aggb, stats, g0, be0, hb, total4, invN, 0);

  // ---- layers 1,2: GEMM(xdinv) -> aggregate(+bias,+stats) -> BN ----
  const float* bs[2]  = {b1, b2};
  const float* gs[2]  = {g1, g2};
  const float* bes[2] = {be1, be2};
  const ushort* Wts[2] = {Wt1, Wt2};
  for (int L = 0; L < 2; L++) {
    gemm_mfma_k<256,0><<<nb, 256, 0, stream>>>(hb, Wts[L], dinv, bs[L], y, aggb, stats, N_);
    hipMemsetAsync(stats, 0, 2*H*4, stream);
    aggregate_k<<<512, 1024, 0, stream>>>(y, csr, rowptr, dinv, bs[L], aggb, stats, N_);
    bn_apply_k<<<2048, 256, 0, stream>>>(aggb, stats, gs[L], bes[L], hb, total4, invN, 1);
  }

  pool_k<<<G_, H, 0, stream>>>(hb, gstart, pooled);
  mlp_k<<<G_, 128, 0, stream>>>(pooled, mW1, mb1, mW2, mb2, out);
}